// Round 8
// baseline (227.346 us; speedup 1.0000x reference)
//
#include <hip/hip_runtime.h>
#include <math.h>

#define CDIM 768
#define NHEADS 12
#define HDIM 64
#define BATCH 4
#define SEQ 2048
#define MTOT (BATCH*SEQ)     // 8192
#define NQKV (3*CDIM)        // 2304
#define QROWS 128            // Q rows per attention block
#define VTILE 4096           // u16 elements per fragmented V tile (2 blk * 4 jd * 64 lane * 8)

typedef __attribute__((ext_vector_type(8))) short bf16x8;
typedef __attribute__((ext_vector_type(4))) float f32x4;
typedef unsigned short u16;
typedef unsigned int u32;

// async global->LDS, 16B per lane. LDS dest must be wave-uniform base + lane*16
// (global source address is per-lane free-form).
#define ASYNC16(gsrc, ldst) \
  __builtin_amdgcn_global_load_lds((const __attribute__((address_space(1))) void*)(gsrc), \
                                   (__attribute__((address_space(3))) void*)(ldst), 16, 0, 0)

// RNE fp32->bf16 (finite inputs only)
__device__ inline u16 f2b(float x) {
    unsigned int u = __float_as_uint(x);
    return (u16)((u + 0x7fffu + ((u >> 16) & 1u)) >> 16);
}
// rounding-biased uint for pack: hi16(u+0x8000) = round-half-up-in-magnitude bf16
__device__ inline u32 prnd(float x) { return __float_as_uint(x) + 0x8000u; }

// ---------------------------------------------------------------------------
// Fused prologue: x cast (6144 blocks) + 4 weight casts (4*576) + bias concat (9)
// ---------------------------------------------------------------------------
#define XBLK (MTOT*CDIM/1024)        // 6144
#define WBLK (CDIM*CDIM/1024)        // 576
__global__ __launch_bounds__(256)
void prep_kern(const float* __restrict__ x,
               const float* __restrict__ Wq, const float* __restrict__ Wk,
               const float* __restrict__ Wv, const float* __restrict__ Wo,
               const float* __restrict__ bq, const float* __restrict__ bk,
               const float* __restrict__ bv,
               u16* __restrict__ xb, u16* __restrict__ wqkv, u16* __restrict__ wob,
               float* __restrict__ bcat)
{
    int bx = blockIdx.x, tid = threadIdx.x;
    if (bx < XBLK) {
        int i = (bx * 256 + tid) * 4;
        float4 v = *(const float4*)(x + i);
        ushort4 o;
        o.x = f2b(v.x); o.y = f2b(v.y); o.z = f2b(v.z); o.w = f2b(v.w);
        *(ushort4*)(xb + i) = o;
    } else if (bx < XBLK + 4*WBLK) {
        int z = (bx - XBLK) / WBLK;
        int blk = (bx - XBLK) % WBLK;
        const float* src = (z == 0) ? Wq : (z == 1) ? Wk : (z == 2) ? Wv : Wo;
        u16* dst = (z == 3) ? wob : wqkv + (size_t)z * CDIM * CDIM;
        int i = (blk * 256 + tid) * 4;
        float4 v = *(const float4*)(src + i);
        ushort4 o;
        o.x = f2b(v.x); o.y = f2b(v.y); o.z = f2b(v.z); o.w = f2b(v.w);
        *(ushort4*)(dst + i) = o;
    } else {
        int i = (bx - XBLK - 4*WBLK) * 256 + tid;
        if (i < CDIM) bcat[i] = bq[i];
        else if (i < 2*CDIM) bcat[i] = bk[i - CDIM];
        else if (i < 3*CDIM) bcat[i] = bv[i - 2*CDIM];
    }
}

// ---------------------------------------------------------------------------
// bf16 GEMM: Y[m,n] = (sum_k A[m,k]*B[n,k] + bias[n]) * (n<qn ? qscale : 1)
// 128x128 tile, BK=64, 4 waves (2x2 of 64x64), 16x16x32 MFMA, XOR-swizzled
// global_load_lds staging, DOUBLE-BUFFERED (T3 minimum-2-phase).
// XCD-aware block swizzle (T1): FETCH 70.6MB -> L2-local panels.
// VFRAG=1: tiles with n0>=1536 (the V columns of the QKV GEMM) are written
// as pre-packed PV fragments into Vt instead of rows into Y.
// Fragment layout (matched to 16x16x32 PV MFMA, semantic k within a 32-key
// block: k(quad,j) = j<4 ? 4*quad+j : 16+4*quad+(j-4)):
//   epilogue element (i,j',r): seq s64 = i*16+quad*4+r -> t=i>>1,
//   word wj = 4*(i&1)+r, fragment lane = quad*16 + l15, jd = j'.
//   Vt[(bh*32+kt)*VTILE + ((t*4+jd)*64 + lane)*8 + 4*(i&1) + r]
// ---------------------------------------------------------------------------
template<int OUTF32, int VFRAG>
__global__ __launch_bounds__(256)
void gemm_bf16(const u16* __restrict__ A, const u16* __restrict__ B,
               const float* __restrict__ bias, void* __restrict__ Y,
               u16* __restrict__ Vt,
               int N, int K, int qn, float qscale)
{
    __shared__ __align__(16) u16 As[2][128*64];
    __shared__ __align__(16) u16 Bs[2][128*64];
    const int tid = threadIdx.x;
    // ---- XCD swizzle: nwg % 8 == 0 for all launches (1152 / 384) ----
    const int nwg = gridDim.x * gridDim.y;
    const int fid = blockIdx.y * gridDim.x + blockIdx.x;
    const int swz = (fid & 7) * (nwg >> 3) + (fid >> 3);
    const int m0 = (swz / gridDim.x) * 128, n0 = (swz % gridDim.x) * 128;
    const int wid = tid >> 6, lane = tid & 63;
    const int wm = (wid & 1) * 64, wn = (wid >> 1) * 64;
    const int l15 = lane & 15, quad = lane >> 4;

    f32x4 acc[4][4];
    #pragma unroll
    for (int i = 0; i < 4; ++i)
        #pragma unroll
        for (int j = 0; j < 4; ++j)
            #pragma unroll
            for (int r = 0; r < 4; ++r) acc[i][j][r] = 0.f;

    auto stage = [&](int buf, int t) {
        int k0 = t * 64;
        #pragma unroll
        for (int r = 0; r < 4; ++r) {
            int li = r*256 + tid;
            int row = li >> 3, c = li & 7;
            int gc = c ^ (row & 7);
            ASYNC16(A + (size_t)(m0 + row) * K + k0 + gc*8, &As[buf][li*8]);
            ASYNC16(B + (size_t)(n0 + row) * K + k0 + gc*8, &Bs[buf][li*8]);
        }
    };

    const int NT = K / 64;
    stage(0, 0);
    __syncthreads();                       // drains prologue asyncs

    for (int t = 0; t < NT; ++t) {
        const int bufc = t & 1;
        if (t + 1 < NT) stage(bufc ^ 1, t + 1);   // overlap with MFMA below
        #pragma unroll
        for (int kk = 0; kk < 2; ++kk) {
            bf16x8 a[4], b[4];
            #pragma unroll
            for (int i = 0; i < 4; ++i) {
                int m = wm + i*16 + l15;
                int ca = (kk*4 + quad) ^ (m & 7);
                a[i] = *(const bf16x8*)&As[bufc][m*64 + ca*8];
                int n = wn + i*16 + l15;
                int cbx = (kk*4 + quad) ^ (n & 7);
                b[i] = *(const bf16x8*)&Bs[bufc][n*64 + cbx*8];
            }
            #pragma unroll
            for (int i = 0; i < 4; ++i)
                #pragma unroll
                for (int j = 0; j < 4; ++j)
                    acc[i][j] = __builtin_amdgcn_mfma_f32_16x16x32_bf16(a[i], b[j], acc[i][j], 0, 0, 0);
        }
        __syncthreads();   // drains next-tile asyncs; protects buffer reuse
    }

    if (VFRAG && n0 >= 2*CDIM) {
        // ---- V tile: write PV 16x16x32 B-fragments straight to Vt ----
        #pragma unroll
        for (int i = 0; i < 4; ++i) {
            int gm = m0 + wm + i*16 + quad*4;      // seq base for r=0..3
            int bb = gm >> 11;                     // batch
            int kt = (gm & 2047) >> 6;             // 64-key tile
            int t  = i >> 1;                       // 32-key block within tile
            int wj = (i & 1) * 4;                  // word offset in fragment
            #pragma unroll
            for (int j = 0; j < 4; ++j) {
                int gn = n0 + wn + j*16 + l15;
                float bv = bias[gn];
                int d = gn - 2*CDIM;
                int h = d >> 6, jd = (d & 63) >> 4;  // jd == j
                int bh = bb * NHEADS + h;
                u32 p0 = prnd(acc[i][j][0] + bv);
                u32 p1 = prnd(acc[i][j][1] + bv);
                u32 p2 = prnd(acc[i][j][2] + bv);
                u32 p3 = prnd(acc[i][j][3] + bv);
                uint2 st;
                st.x = __builtin_amdgcn_perm(p1, p0, 0x07060302u);
                st.y = __builtin_amdgcn_perm(p3, p2, 0x07060302u);
                *(uint2*)(Vt + ((size_t)(bh*32 + kt))*VTILE
                             + (size_t)((t*4 + jd)*64 + lane)*8 + wj) = st;
            }
        }
    } else {
        #pragma unroll
        for (int i = 0; i < 4; ++i) {
            #pragma unroll
            for (int j = 0; j < 4; ++j) {
                int gn = n0 + wn + j*16 + l15;
                float bv = bias[gn];
                float sc = (gn < qn) ? qscale : 1.0f;
                #pragma unroll
                for (int r = 0; r < 4; ++r) {
                    int gm = m0 + wm + i*16 + quad*4 + r;
                    float v = (acc[i][j][r] + bv) * sc;
                    if (OUTF32) ((float*)Y)[(size_t)gm * N + gn] = v;
                    else        ((u16*)Y)[(size_t)gm * N + gn] = f2b(v);
                }
            }
        }
    }
}

// ---------------------------------------------------------------------------
// MFMA flash attention, CROSS-TILE SOFTWARE-PIPELINED (T15-style).
// Round-7 counters: FETCH 18.5MB (L2-local), HBM 6.4%, MfmaUtil 38 + VALU 45
// = 83% issue-bound -> the S->pack->PV chain serializes the two pipes.
// New schedule per step kt: issue prefetch(kt+1); load vfC(kt); S(kt) MFMAs
// (independent) OVERLAP pack(kt-1) VALU; then PV(kt-1) MFMAs; barrier.
// s and vf carried across the barrier in explicit A/B register states
// (compile-time indexed — rule #20). launch_bounds(256,2): peak live regs
// ~200, spill >> occupancy cost (measured residency was ~2 blocks anyway).
// V split (t=0 LDS-staged / t=1 direct-global) and XCD swizzle kept.
// ---------------------------------------------------------------------------
__global__ __launch_bounds__(256, 2)
void attn_mfma(const u16* __restrict__ QK, const u16* __restrict__ Vt,
               u16* __restrict__ Oa)
{
    __shared__ __align__(16) u16 Ks[2][64*64];
    __shared__ __align__(16) u16 Vls[2][2048];   // t=0 fragment half (4 KB)

    const int tid = threadIdx.x;
    const int wid = tid >> 6, lane = tid & 63;
    const int l15 = lane & 15, quad = lane >> 4;
    // ---- XCD swizzle: nwg = 16*48 = 768, 96 logical blocks per XCD ----
    const int fid = blockIdx.y * gridDim.x + blockIdx.x;
    const int swz = (fid & 7) * 96 + (fid >> 3);
    const int qt = swz & 15, bh = swz >> 4;
    const int b = bh / NHEADS, h = bh % NHEADS;

    const u16* Qg  = QK + ((size_t)(b*SEQ + qt*QROWS)) * NQKV + h*HDIM;
    const u16* Kg0 = QK + ((size_t)(b*SEQ)) * NQKV + CDIM + h*HDIM;
    const u16* Vg  = Vt + (size_t)bh * 32 * VTILE;   // + kt*VTILE per tile

    // ---- prologue: stage K0 + V0(t=0 half); Q frags straight to registers ----
    #pragma unroll
    for (int r = 0; r < 2; ++r) {
        int li = r*256 + tid, row = li >> 3, c = li & 7, gc = c ^ (row & 7);
        ASYNC16(Kg0 + (size_t)row * NQKV + gc*8, &Ks[0][li*8]);
    }
    ASYNC16(Vg + tid*8, &Vls[0][tid*8]);

    // Q as B-operand of 16x16x32: B[n=l15][k=quad*8+jj]
    bf16x8 qf[2][2];
    #pragma unroll
    for (int mb = 0; mb < 2; ++mb)
        #pragma unroll
        for (int kk = 0; kk < 2; ++kk)
            qf[mb][kk] = *(const bf16x8*)(Qg + (size_t)(wid*32 + mb*16 + l15) * NQKV + kk*32 + quad*8);

    const bf16x8 ONES8 = { (short)0x3F80, (short)0x3F80, (short)0x3F80, (short)0x3F80,
                           (short)0x3F80, (short)0x3F80, (short)0x3F80, (short)0x3F80 };
    const f32x4 ZERO4 = { 0.f, 0.f, 0.f, 0.f };

    f32x4 o[2][4];
    #pragma unroll
    for (int mb = 0; mb < 2; ++mb)
        #pragma unroll
        for (int j = 0; j < 4; ++j)
            #pragma unroll
            for (int r = 0; r < 4; ++r) o[mb][j][r] = 0.f;
    f32x4 ll[2];
    #pragma unroll
    for (int mb = 0; mb < 2; ++mb)
        #pragma unroll
        for (int r = 0; r < 4; ++r) ll[mb][r] = 0.f;

    // pipeline register state (explicit A/B, compile-time indexed)
    f32x4 sA[2][4], sB[2][4];
    bf16x8 vfA[2][4], vfB[2][4];

    __syncthreads();

    // finish tile kt-1: pack P from sP, PV with vfP
    auto finish = [&](f32x4 (&sP)[2][4], bf16x8 (&vfP)[2][4]) {
        bf16x8 pf[2][2];
        #pragma unroll
        for (int mb = 0; mb < 2; ++mb)
            #pragma unroll
            for (int t = 0; t < 2; ++t) {
                u32 a0 = prnd(__builtin_amdgcn_exp2f(sP[mb][2*t][0]));
                u32 a1 = prnd(__builtin_amdgcn_exp2f(sP[mb][2*t][1]));
                u32 a2 = prnd(__builtin_amdgcn_exp2f(sP[mb][2*t][2]));
                u32 a3 = prnd(__builtin_amdgcn_exp2f(sP[mb][2*t][3]));
                u32 b0 = prnd(__builtin_amdgcn_exp2f(sP[mb][2*t+1][0]));
                u32 b1 = prnd(__builtin_amdgcn_exp2f(sP[mb][2*t+1][1]));
                u32 b2 = prnd(__builtin_amdgcn_exp2f(sP[mb][2*t+1][2]));
                u32 b3 = prnd(__builtin_amdgcn_exp2f(sP[mb][2*t+1][3]));
                union { uint4 u; bf16x8 v; } cst;
                cst.u.x = __builtin_amdgcn_perm(a1, a0, 0x07060302u);
                cst.u.y = __builtin_amdgcn_perm(a3, a2, 0x07060302u);
                cst.u.z = __builtin_amdgcn_perm(b1, b0, 0x07060302u);
                cst.u.w = __builtin_amdgcn_perm(b3, b2, 0x07060302u);
                pf[mb][t] = cst.v;
            }
        __builtin_amdgcn_s_setprio(1);
        #pragma unroll
        for (int t = 0; t < 2; ++t) {
            #pragma unroll
            for (int jd = 0; jd < 4; ++jd) {
                #pragma unroll
                for (int mb = 0; mb < 2; ++mb)
                    o[mb][jd] = __builtin_amdgcn_mfma_f32_16x16x32_bf16(pf[mb][t], vfP[t][jd], o[mb][jd], 0, 0, 0);
            }
            #pragma unroll
            for (int mb = 0; mb < 2; ++mb)
                ll[mb] = __builtin_amdgcn_mfma_f32_16x16x32_bf16(pf[mb][t], ONES8, ll[mb], 0, 0, 0);
        }
        __builtin_amdgcn_s_setprio(0);
    };

    // step kt: prefetch kt+1, V-frag loads for kt, S(kt) MFMAs; overlap
    // finish(kt-1); barrier.
    auto step = [&](int kt, int cbuf, int nbuf,
                    f32x4 (&sP)[2][4], bf16x8 (&vfP)[2][4],
                    f32x4 (&sC)[2][4], bf16x8 (&vfC)[2][4], bool first) {
        if (kt + 1 < SEQ/64) {
            #pragma unroll
            for (int r = 0; r < 2; ++r) {
                int li = r*256 + tid, row = li >> 3, c = li & 7, gc = c ^ (row & 7);
                ASYNC16(Kg0 + (size_t)((kt+1)*64 + row) * NQKV + gc*8, &Ks[nbuf][li*8]);
            }
            ASYNC16(Vg + (size_t)(kt+1) * VTILE + tid*8, &Vls[nbuf][tid*8]);
        }

        // V fragments for tile kt (consumed next step): t=0 LDS, t=1 global
        #pragma unroll
        for (int jd = 0; jd < 4; ++jd) {
            vfC[0][jd] = *(const bf16x8*)&Vls[cbuf][(size_t)(jd*64 + lane)*8];
            vfC[1][jd] = *(const bf16x8*)(Vg + (size_t)kt * VTILE
                                          + (size_t)((4 + jd)*64 + lane)*8);
        }

        // S^T(kt) = K.Q^T — independent of finish(kt-1); compiler interleaves
        __builtin_amdgcn_s_setprio(1);
        #pragma unroll
        for (int j = 0; j < 4; ++j) {
            int kr = j*16 + l15;
            int ck = quad ^ (kr & 7);
            bf16x8 ak = *(const bf16x8*)&Ks[cbuf][kr*64 + ck*8];
            #pragma unroll
            for (int mb = 0; mb < 2; ++mb)
                sC[mb][j] = __builtin_amdgcn_mfma_f32_16x16x32_bf16(ak, qf[mb][0], ZERO4, 0, 0, 0);
        }
        #pragma unroll
        for (int j = 0; j < 4; ++j) {
            int kr = j*16 + l15;
            int ck = (4 + quad) ^ (kr & 7);
            bf16x8 ak = *(const bf16x8*)&Ks[cbuf][kr*64 + ck*8];
            #pragma unroll
            for (int mb = 0; mb < 2; ++mb)
                sC[mb][j] = __builtin_amdgcn_mfma_f32_16x16x32_bf16(ak, qf[mb][1], sC[mb][j], 0, 0, 0);
        }
        __builtin_amdgcn_s_setprio(0);

        if (!first) finish(sP, vfP);   // pack(kt-1) VALU + PV(kt-1) MFMA

        __syncthreads();   // drains next-tile asyncs; protects buffer reuse
    };

    // 32 tiles: step k uses cbuf = k&1; s/vf alternate A (even) / B (odd)
    step(0, 0, 1, sB, vfB, sA, vfA, true);
    for (int kt = 1; kt < 31; kt += 2) {
        step(kt,   1, 0, sA, vfA, sB, vfB, false);
        step(kt+1, 0, 1, sB, vfB, sA, vfA, false);
    }
    step(31, 1, 0, sA, vfA, sB, vfB, false);
    finish(sB, vfB);   // drain tile 31

    // ---- epilogue: O rows q = quad*4+r, cols d = jd*16+l15; l same layout ----
    u16* Og = Oa + ((size_t)(b*SEQ + qt*QROWS)) * CDIM + h*HDIM;
    #pragma unroll
    for (int mb = 0; mb < 2; ++mb) {
        #pragma unroll
        for (int r = 0; r < 4; ++r) {
            float inv = 1.f / ll[mb][r];
            int row = wid*32 + mb*16 + quad*4 + r;
            #pragma unroll
            for (int jd = 0; jd < 4; ++jd)
                Og[(size_t)row * CDIM + jd*16 + l15] = f2b(o[mb][jd][r] * inv);
        }
    }
}

// ---------------------------------------------------------------------------
extern "C" void kernel_launch(void* const* d_in, const int* in_sizes, int n_in,
                              void* d_out, int out_size, void* d_ws, size_t ws_size,
                              hipStream_t stream)
{
    const float* x  = (const float*)d_in[0];
    const float* Wq = (const float*)d_in[1];
    const float* bq = (const float*)d_in[2];
    const float* Wk = (const float*)d_in[3];
    const float* bk = (const float*)d_in[4];
    const float* Wv = (const float*)d_in[5];
    const float* bv = (const float*)d_in[6];
    const float* Wo = (const float*)d_in[7];
    const float* bo = (const float*)d_in[8];

    unsigned char* ws = (unsigned char*)d_ws;
    u16* xb   = (u16*)ws;  ws += (size_t)MTOT * CDIM * 2;
    u16* wqkv = (u16*)ws;  ws += (size_t)NQKV * CDIM * 2;
    u16* wob  = (u16*)ws;  ws += (size_t)CDIM * CDIM * 2;
    float* bcat = (float*)ws; ws += (size_t)NQKV * 4;
    u16* qkv  = (u16*)ws;  ws += (size_t)MTOT * NQKV * 2;
    u16* vt   = (u16*)ws;  ws += (size_t)BATCH*NHEADS*32*VTILE * 2;
    u16* ao   = (u16*)ws;

    prep_kern<<<XBLK + 4*WBLK + 9, 256, 0, stream>>>(x, Wq, Wk, Wv, Wo, bq, bk, bv,
                                                     xb, wqkv, wob, bcat);

    // q pre-scaled by log2(e)/sqrt(HDIM) so softmax is a bare exp2
    gemm_bf16<0,1><<<dim3(NQKV/128, MTOT/128), 256, 0, stream>>>(xb, wqkv, bcat, qkv, vt, NQKV, CDIM, CDIM, 0.18033688f);
    attn_mfma<<<dim3(SEQ/QROWS, BATCH*NHEADS), 256, 0, stream>>>(qkv, vt, ao);
    gemm_bf16<1,0><<<dim3(CDIM/128, MTOT/128), 256, 0, stream>>>(ao, wob, bo, (float*)d_out, nullptr, CDIM, CDIM, 0, 1.0f);
}

// Round 9
// 225.993 us; speedup vs baseline: 1.0060x; 1.0060x over previous
//
#include <hip/hip_runtime.h>
#include <math.h>

#define CDIM 768
#define NHEADS 12
#define HDIM 64
#define BATCH 4
#define SEQ 2048
#define MTOT (BATCH*SEQ)     // 8192
#define NQKV (3*CDIM)        // 2304
#define QROWS 128            // Q rows per attention block
#define VTILE 4096           // u16 elements per fragmented V tile (2 blk * 4 jd * 64 lane * 8)

typedef __attribute__((ext_vector_type(8))) short bf16x8;
typedef __attribute__((ext_vector_type(4))) float f32x4;
typedef unsigned short u16;
typedef unsigned int u32;

// async global->LDS, 16B per lane. LDS dest must be wave-uniform base + lane*16
// (global source address is per-lane free-form).
#define ASYNC16(gsrc, ldst) \
  __builtin_amdgcn_global_load_lds((const __attribute__((address_space(1))) void*)(gsrc), \
                                   (__attribute__((address_space(3))) void*)(ldst), 16, 0, 0)

// RNE fp32->bf16 (finite inputs only)
__device__ inline u16 f2b(float x) {
    unsigned int u = __float_as_uint(x);
    return (u16)((u + 0x7fffu + ((u >> 16) & 1u)) >> 16);
}
// rounding-biased uint for pack: hi16(u+0x8000) = round-half-up-in-magnitude bf16
__device__ inline u32 prnd(float x) { return __float_as_uint(x) + 0x8000u; }

// ---------------------------------------------------------------------------
// Fused prologue: x cast (6144 blocks) + 4 weight casts (4*576) + bias concat (9)
// ---------------------------------------------------------------------------
#define XBLK (MTOT*CDIM/1024)        // 6144
#define WBLK (CDIM*CDIM/1024)        // 576
__global__ __launch_bounds__(256)
void prep_kern(const float* __restrict__ x,
               const float* __restrict__ Wq, const float* __restrict__ Wk,
               const float* __restrict__ Wv, const float* __restrict__ Wo,
               const float* __restrict__ bq, const float* __restrict__ bk,
               const float* __restrict__ bv,
               u16* __restrict__ xb, u16* __restrict__ wqkv, u16* __restrict__ wob,
               float* __restrict__ bcat)
{
    int bx = blockIdx.x, tid = threadIdx.x;
    if (bx < XBLK) {
        int i = (bx * 256 + tid) * 4;
        float4 v = *(const float4*)(x + i);
        ushort4 o;
        o.x = f2b(v.x); o.y = f2b(v.y); o.z = f2b(v.z); o.w = f2b(v.w);
        *(ushort4*)(xb + i) = o;
    } else if (bx < XBLK + 4*WBLK) {
        int z = (bx - XBLK) / WBLK;
        int blk = (bx - XBLK) % WBLK;
        const float* src = (z == 0) ? Wq : (z == 1) ? Wk : (z == 2) ? Wv : Wo;
        u16* dst = (z == 3) ? wob : wqkv + (size_t)z * CDIM * CDIM;
        int i = (blk * 256 + tid) * 4;
        float4 v = *(const float4*)(src + i);
        ushort4 o;
        o.x = f2b(v.x); o.y = f2b(v.y); o.z = f2b(v.z); o.w = f2b(v.w);
        *(ushort4*)(dst + i) = o;
    } else {
        int i = (bx - XBLK - 4*WBLK) * 256 + tid;
        if (i < CDIM) bcat[i] = bq[i];
        else if (i < 2*CDIM) bcat[i] = bk[i - CDIM];
        else if (i < 3*CDIM) bcat[i] = bv[i - 2*CDIM];
    }
}

// ---------------------------------------------------------------------------
// bf16 GEMM: Y[m,n] = (sum_k A[m,k]*B[n,k] + bias[n]) * (n<qn ? qscale : 1)
// 128x128 tile, BK=32, 4 waves (2x2 of 64x64), 16x16x32 MFMA, XOR-swizzled
// global_load_lds staging, TRIPLE-BUFFERED with counted vmcnt (T4):
// round-6's 2-buffer version still drained vmcnt(0) at every barrier
// (__syncthreads semantics) so the 1-deep prefetch bought little (m97
// ceiling mechanism). Here: issue stage(t+2); ds_read+MFMA(t);
// s_waitcnt vmcnt(4) -> only stage(t+1) must land, stage(t+2)'s 4 loads
// stay in flight ACROSS the raw s_barrier. LDS 3x16KB = 48KB -> 3
// blocks/CU (vs 2 at BK=64 dbuf). Per-wave ds_reads are all MFMA-consumed
// before the barrier (compiler lgkmcnt), so raw s_barrier is safe.
// XCD-aware block swizzle (T1): FETCH 70.6MB -> L2-local panels.
// VFRAG=1: tiles with n0>=1536 (the V columns of the QKV GEMM) are written
// as pre-packed PV fragments into Vt instead of rows into Y.
// Fragment layout (matched to 16x16x32 PV MFMA, semantic k within a 32-key
// block: k(quad,j) = j<4 ? 4*quad+j : 16+4*quad+(j-4)):
//   epilogue element (i,j',r): seq s64 = i*16+quad*4+r -> t=i>>1,
//   word wj = 4*(i&1)+r, fragment lane = quad*16 + l15, jd = j'.
//   Vt[(bh*32+kt)*VTILE + ((t*4+jd)*64 + lane)*8 + 4*(i&1) + r]
// ---------------------------------------------------------------------------
template<int OUTF32, int VFRAG>
__global__ __launch_bounds__(256)
void gemm_bf16(const u16* __restrict__ A, const u16* __restrict__ B,
               const float* __restrict__ bias, void* __restrict__ Y,
               u16* __restrict__ Vt,
               int N, int K, int qn, float qscale)
{
    __shared__ __align__(16) u16 As[3][128*32];
    __shared__ __align__(16) u16 Bs[3][128*32];
    const int tid = threadIdx.x;
    // ---- XCD swizzle: nwg % 8 == 0 for all launches (1152 / 384) ----
    const int nwg = gridDim.x * gridDim.y;
    const int fid = blockIdx.y * gridDim.x + blockIdx.x;
    const int swz = (fid & 7) * (nwg >> 3) + (fid >> 3);
    const int m0 = (swz / gridDim.x) * 128, n0 = (swz % gridDim.x) * 128;
    const int wid = tid >> 6, lane = tid & 63;
    const int wm = (wid & 1) * 64, wn = (wid >> 1) * 64;
    const int l15 = lane & 15, quad = lane >> 4;

    f32x4 acc[4][4];
    #pragma unroll
    for (int i = 0; i < 4; ++i)
        #pragma unroll
        for (int j = 0; j < 4; ++j)
            #pragma unroll
            for (int r = 0; r < 4; ++r) acc[i][j][r] = 0.f;

    // stage one BK=32 tile (8KB per array): 4 vmcnt ops/thread
    auto stage = [&](int buf, int t) {
        int k0 = t * 32;
        #pragma unroll
        for (int r = 0; r < 2; ++r) {
            int li = r*256 + tid;
            int row = li >> 2, c = li & 3;
            int gc = c ^ (row & 3);
            ASYNC16(A + (size_t)(m0 + row) * K + k0 + gc*8, &As[buf][li*8]);
            ASYNC16(B + (size_t)(n0 + row) * K + k0 + gc*8, &Bs[buf][li*8]);
        }
    };

    const int NT = K / 32;                 // 24 for K=768
    stage(0, 0);
    if (NT > 1) stage(1, 1);
    asm volatile("s_waitcnt vmcnt(4)" ::: "memory");   // stage(0) landed
    __builtin_amdgcn_s_barrier();

    int bufc = 0, bufp = 2;                // compute buf, prefetch buf (t+2)
    for (int t = 0; t < NT; ++t) {
        const bool more = (t + 2 < NT);
        if (more) stage(bufp, t + 2);      // 4 loads stay in flight past barrier

        bf16x8 a[4], b[4];
        #pragma unroll
        for (int i = 0; i < 4; ++i) {
            int m = wm + i*16 + l15;
            int ca = quad ^ (m & 3);
            a[i] = *(const bf16x8*)&As[bufc][m*32 + ca*8];
            int n = wn + i*16 + l15;
            int cbx = quad ^ (n & 3);
            b[i] = *(const bf16x8*)&Bs[bufc][n*32 + cbx*8];
        }
        #pragma unroll
        for (int i = 0; i < 4; ++i)
            #pragma unroll
            for (int j = 0; j < 4; ++j)
                acc[i][j] = __builtin_amdgcn_mfma_f32_16x16x32_bf16(a[i], b[j], acc[i][j], 0, 0, 0);

        if (more) asm volatile("s_waitcnt vmcnt(4)" ::: "memory"); // t+1 landed
        else      asm volatile("s_waitcnt vmcnt(0)" ::: "memory"); // tail drain
        __builtin_amdgcn_s_barrier();
        bufc = (bufc == 2) ? 0 : bufc + 1;
        bufp = (bufp == 2) ? 0 : bufp + 1;
    }

    if (VFRAG && n0 >= 2*CDIM) {
        // ---- V tile: write PV 16x16x32 B-fragments straight to Vt ----
        #pragma unroll
        for (int i = 0; i < 4; ++i) {
            int gm = m0 + wm + i*16 + quad*4;      // seq base for r=0..3
            int bb = gm >> 11;                     // batch
            int kt = (gm & 2047) >> 6;             // 64-key tile
            int t  = i >> 1;                       // 32-key block within tile
            int wj = (i & 1) * 4;                  // word offset in fragment
            #pragma unroll
            for (int j = 0; j < 4; ++j) {
                int gn = n0 + wn + j*16 + l15;
                float bv = bias[gn];
                int d = gn - 2*CDIM;
                int h = d >> 6, jd = (d & 63) >> 4;  // jd == j
                int bh = bb * NHEADS + h;
                u32 p0 = prnd(acc[i][j][0] + bv);
                u32 p1 = prnd(acc[i][j][1] + bv);
                u32 p2 = prnd(acc[i][j][2] + bv);
                u32 p3 = prnd(acc[i][j][3] + bv);
                uint2 st;
                st.x = __builtin_amdgcn_perm(p1, p0, 0x07060302u);
                st.y = __builtin_amdgcn_perm(p3, p2, 0x07060302u);
                *(uint2*)(Vt + ((size_t)(bh*32 + kt))*VTILE
                             + (size_t)((t*4 + jd)*64 + lane)*8 + wj) = st;
            }
        }
    } else {
        #pragma unroll
        for (int i = 0; i < 4; ++i) {
            #pragma unroll
            for (int j = 0; j < 4; ++j) {
                int gn = n0 + wn + j*16 + l15;
                float bv = bias[gn];
                float sc = (gn < qn) ? qscale : 1.0f;
                #pragma unroll
                for (int r = 0; r < 4; ++r) {
                    int gm = m0 + wm + i*16 + quad*4 + r;
                    float v = (acc[i][j][r] + bv) * sc;
                    if (OUTF32) ((float*)Y)[(size_t)gm * N + gn] = v;
                    else        ((u16*)Y)[(size_t)gm * N + gn] = f2b(v);
                }
            }
        }
    }
}

// ---------------------------------------------------------------------------
// MFMA flash attention (round-7 version — the T15 cross-tile pipeline of
// round 8 regressed 61.5->79.5us by dropping occupancy 3->2 blocks/CU;
// reverted). S^T = K.Q^T, exp2 in-register (log2e folded into q upstream),
// P packed via prnd+v_perm into bf16x8 A-fragments with consistent semantic
// k (matches the V fragment layout from the QKV GEMM epilogue -> PV is
// full-rate 16x16x32 MFMA, no cross-lane shuffle). Zero-C first S-half.
// V split: t=0 half LDS-staged (dbuf), t=1 half direct-global (pipe
// balance, rounds 2/4). K LDS-staged dbuf XOR-swizzled. 1 barrier/tile.
// setprio(1) around MFMA clusters (T5). XCD swizzle (T1): FETCH 104->18.5MB.
// ---------------------------------------------------------------------------
__global__ __launch_bounds__(256, 3)
void attn_mfma(const u16* __restrict__ QK, const u16* __restrict__ Vt,
               u16* __restrict__ Oa)
{
    __shared__ __align__(16) u16 Ks[2][64*64];
    __shared__ __align__(16) u16 Vls[2][2048];   // t=0 fragment half (4 KB)

    const int tid = threadIdx.x;
    const int wid = tid >> 6, lane = tid & 63;
    const int l15 = lane & 15, quad = lane >> 4;
    // ---- XCD swizzle: nwg = 16*48 = 768, 96 logical blocks per XCD ----
    const int fid = blockIdx.y * gridDim.x + blockIdx.x;
    const int swz = (fid & 7) * 96 + (fid >> 3);
    const int qt = swz & 15, bh = swz >> 4;
    const int b = bh / NHEADS, h = bh % NHEADS;

    const u16* Qg  = QK + ((size_t)(b*SEQ + qt*QROWS)) * NQKV + h*HDIM;
    const u16* Kg0 = QK + ((size_t)(b*SEQ)) * NQKV + CDIM + h*HDIM;
    const u16* Vg  = Vt + (size_t)bh * 32 * VTILE;   // + kt*VTILE per tile

    // ---- prologue: stage K0 + V0(t=0 half); Q frags straight to registers ----
    #pragma unroll
    for (int r = 0; r < 2; ++r) {
        int li = r*256 + tid, row = li >> 3, c = li & 7, gc = c ^ (row & 7);
        ASYNC16(Kg0 + (size_t)row * NQKV + gc*8, &Ks[0][li*8]);
    }
    ASYNC16(Vg + tid*8, &Vls[0][tid*8]);

    // Q as B-operand of 16x16x32: B[n=l15][k=quad*8+jj]
    bf16x8 qf[2][2];
    #pragma unroll
    for (int mb = 0; mb < 2; ++mb)
        #pragma unroll
        for (int kk = 0; kk < 2; ++kk)
            qf[mb][kk] = *(const bf16x8*)(Qg + (size_t)(wid*32 + mb*16 + l15) * NQKV + kk*32 + quad*8);

    const bf16x8 ONES8 = { (short)0x3F80, (short)0x3F80, (short)0x3F80, (short)0x3F80,
                           (short)0x3F80, (short)0x3F80, (short)0x3F80, (short)0x3F80 };
    const f32x4 ZERO4 = { 0.f, 0.f, 0.f, 0.f };

    f32x4 o[2][4];
    #pragma unroll
    for (int mb = 0; mb < 2; ++mb)
        #pragma unroll
        for (int j = 0; j < 4; ++j)
            #pragma unroll
            for (int r = 0; r < 4; ++r) o[mb][j][r] = 0.f;
    f32x4 ll[2];
    #pragma unroll
    for (int mb = 0; mb < 2; ++mb)
        #pragma unroll
        for (int r = 0; r < 4; ++r) ll[mb][r] = 0.f;

    __syncthreads();

    auto body = [&](int kt, int cbuf, int nbuf) {
        if (kt + 1 < SEQ/64) {
            #pragma unroll
            for (int r = 0; r < 2; ++r) {
                int li = r*256 + tid, row = li >> 3, c = li & 7, gc = c ^ (row & 7);
                ASYNC16(Kg0 + (size_t)((kt+1)*64 + row) * NQKV + gc*8, &Ks[nbuf][li*8]);
            }
            ASYNC16(Vg + (size_t)(kt+1) * VTILE + tid*8, &Vls[nbuf][tid*8]);
        }

        // ---- V fragments: t=0 from LDS (2-way alias, conflict-free),
        //      t=1 direct from global (coalesced 16B/lane, L2-hit).
        bf16x8 vf[2][4];
        #pragma unroll
        for (int jd = 0; jd < 4; ++jd) {
            vf[0][jd] = *(const bf16x8*)&Vls[cbuf][(size_t)(jd*64 + lane)*8];
            vf[1][jd] = *(const bf16x8*)(Vg + (size_t)kt * VTILE
                                         + (size_t)((4 + jd)*64 + lane)*8);
        }

        // ---- S^T = K.Q^T : s[mb][j][r] = S[q=mb-block+l15][k=j*16+quad*4+r]
        // kk=0 with zero C-operand (no accumulator init), kk=1 accumulates.
        f32x4 s[2][4];
        __builtin_amdgcn_s_setprio(1);
        #pragma unroll
        for (int j = 0; j < 4; ++j) {
            int kr = j*16 + l15;
            int ck = quad ^ (kr & 7);
            bf16x8 ak = *(const bf16x8*)&Ks[cbuf][kr*64 + ck*8];
            #pragma unroll
            for (int mb = 0; mb < 2; ++mb)
                s[mb][j] = __builtin_amdgcn_mfma_f32_16x16x32_bf16(ak, qf[mb][0], ZERO4, 0, 0, 0);
        }
        #pragma unroll
        for (int j = 0; j < 4; ++j) {
            int kr = j*16 + l15;
            int ck = (4 + quad) ^ (kr & 7);
            bf16x8 ak = *(const bf16x8*)&Ks[cbuf][kr*64 + ck*8];
            #pragma unroll
            for (int mb = 0; mb < 2; ++mb)
                s[mb][j] = __builtin_amdgcn_mfma_f32_16x16x32_bf16(ak, qf[mb][1], s[mb][j], 0, 0, 0);
        }
        __builtin_amdgcn_s_setprio(0);

        // ---- p = 2^s in-register; pack to 16x16x32 A-fragments (prnd+perm) ----
        bf16x8 pf[2][2];
        #pragma unroll
        for (int mb = 0; mb < 2; ++mb)
            #pragma unroll
            for (int t = 0; t < 2; ++t) {
                u32 a0 = prnd(__builtin_amdgcn_exp2f(s[mb][2*t][0]));
                u32 a1 = prnd(__builtin_amdgcn_exp2f(s[mb][2*t][1]));
                u32 a2 = prnd(__builtin_amdgcn_exp2f(s[mb][2*t][2]));
                u32 a3 = prnd(__builtin_amdgcn_exp2f(s[mb][2*t][3]));
                u32 b0 = prnd(__builtin_amdgcn_exp2f(s[mb][2*t+1][0]));
                u32 b1 = prnd(__builtin_amdgcn_exp2f(s[mb][2*t+1][1]));
                u32 b2 = prnd(__builtin_amdgcn_exp2f(s[mb][2*t+1][2]));
                u32 b3 = prnd(__builtin_amdgcn_exp2f(s[mb][2*t+1][3]));
                union { uint4 u; bf16x8 v; } cst;
                cst.u.x = __builtin_amdgcn_perm(a1, a0, 0x07060302u);
                cst.u.y = __builtin_amdgcn_perm(a3, a2, 0x07060302u);
                cst.u.z = __builtin_amdgcn_perm(b1, b0, 0x07060302u);
                cst.u.w = __builtin_amdgcn_perm(b3, b2, 0x07060302u);
                pf[mb][t] = cst.v;
            }

        // ---- O += P V ; l += P . 1 ----
        __builtin_amdgcn_s_setprio(1);
        #pragma unroll
        for (int t = 0; t < 2; ++t) {
            #pragma unroll
            for (int jd = 0; jd < 4; ++jd) {
                #pragma unroll
                for (int mb = 0; mb < 2; ++mb)
                    o[mb][jd] = __builtin_amdgcn_mfma_f32_16x16x32_bf16(pf[mb][t], vf[t][jd], o[mb][jd], 0, 0, 0);
            }
            #pragma unroll
            for (int mb = 0; mb < 2; ++mb)
                ll[mb] = __builtin_amdgcn_mfma_f32_16x16x32_bf16(pf[mb][t], ONES8, ll[mb], 0, 0, 0);
        }
        __builtin_amdgcn_s_setprio(0);
        __syncthreads();   // drains next-tile asyncs; protects buffer reuse
    };

    for (int kt = 0; kt < SEQ/64; kt += 2) {
        body(kt,   0, 1);
        body(kt+1, 1, 0);
    }

    // ---- epilogue: O rows q = quad*4+r, cols d = jd*16+l15; l same layout ----
    u16* Og = Oa + ((size_t)(b*SEQ + qt*QROWS)) * CDIM + h*HDIM;
    #pragma unroll
    for (int mb = 0; mb < 2; ++mb) {
        #pragma unroll
        for (int r = 0; r < 4; ++r) {
            float inv = 1.f / ll[mb][r];
            int row = wid*32 + mb*16 + quad*4 + r;
            #pragma unroll
            for (int jd = 0; jd < 4; ++jd)
                Og[(size_t)row * CDIM + jd*16 + l15] = f2b(o[mb][jd][r] * inv);
        }
    }
}

// ---------------------------------------------------------------------------
extern "C" void kernel_launch(void* const* d_in, const int* in_sizes, int n_in,
                              void* d_out, int out_size, void* d_ws, size_t ws_size,
                              hipStream_t stream)
{
    const float* x  = (const float*)d_in[0];
    const float* Wq = (const float*)d_in[1];
    const float* bq = (const float*)d_in[2];
    const float* Wk = (const float*)d_in[3];
    const float* bk = (const float*)d_in[4];
    const float* Wv = (const float*)d_in[5];
    const float* bv = (const float*)d_in[6];
    const float* Wo = (const float*)d_in[7];
    const float* bo = (const float*)d_in[8];

    unsigned char* ws = (unsigned char*)d_ws;
    u16* xb   = (u16*)ws;  ws += (size_t)MTOT * CDIM * 2;
    u16* wqkv = (u16*)ws;  ws += (size_t)NQKV * CDIM * 2;
    u16* wob  = (u16*)ws;  ws += (size_t)CDIM * CDIM * 2;
    float* bcat = (float*)ws; ws += (size_t)NQKV * 4;
    u16* qkv  = (u16*)ws;  ws += (size_t)MTOT * NQKV * 2;
    u16* vt   = (u16*)ws;  ws += (size_t)BATCH*NHEADS*32*VTILE * 2;
    u16* ao   = (u16*)ws;

    prep_kern<<<XBLK + 4*WBLK + 9, 256, 0, stream>>>(x, Wq, Wk, Wv, Wo, bq, bk, bv,
                                                     xb, wqkv, wob, bcat);

    // q pre-scaled by log2(e)/sqrt(HDIM) so softmax is a bare exp2
    gemm_bf16<0,1><<<dim3(NQKV/128, MTOT/128), 256, 0, stream>>>(xb, wqkv, bcat, qkv, vt, NQKV, CDIM, CDIM, 0.18033688f);
    attn_mfma<<<dim3(SEQ/QROWS, BATCH*NHEADS), 256, 0, stream>>>(qkv, vt, ao);
    gemm_bf16<1,0><<<dim3(CDIM/128, MTOT/128), 256, 0, stream>>>(ao, wob, bo, (float*)d_out, nullptr, CDIM, CDIM, 0, 1.0f);
}

// Round 10
// 225.638 us; speedup vs baseline: 1.0076x; 1.0016x over previous
//
#include <hip/hip_runtime.h>
#include <math.h>

#define CDIM 768
#define NHEADS 12
#define HDIM 64
#define BATCH 4
#define SEQ 2048
#define MTOT (BATCH*SEQ)     // 8192
#define NQKV (3*CDIM)        // 2304
#define QROWS 128            // Q rows per attention block
#define VTILE 4096           // u16 elements per fragmented V tile (2 blk * 4 jd * 64 lane * 8)

typedef __attribute__((ext_vector_type(8))) short bf16x8;
typedef __attribute__((ext_vector_type(4))) float f32x4;
typedef unsigned short u16;
typedef unsigned int u32;

// async global->LDS, 16B per lane. LDS dest must be wave-uniform base + lane*16
// (global source address is per-lane free-form).
#define ASYNC16(gsrc, ldst) \
  __builtin_amdgcn_global_load_lds((const __attribute__((address_space(1))) void*)(gsrc), \
                                   (__attribute__((address_space(3))) void*)(ldst), 16, 0, 0)

// RNE fp32->bf16 (finite inputs only)
__device__ inline u16 f2b(float x) {
    unsigned int u = __float_as_uint(x);
    return (u16)((u + 0x7fffu + ((u >> 16) & 1u)) >> 16);
}
// rounding-biased uint for pack: hi16(u+0x8000) = round-half-up-in-magnitude bf16
__device__ inline u32 prnd(float x) { return __float_as_uint(x) + 0x8000u; }

// ---------------------------------------------------------------------------
// Fused prologue: x cast (6144 blocks) + 4 weight casts (4*576) + bias concat (9)
// ---------------------------------------------------------------------------
#define XBLK (MTOT*CDIM/1024)        // 6144
#define WBLK (CDIM*CDIM/1024)        // 576
__global__ __launch_bounds__(256)
void prep_kern(const float* __restrict__ x,
               const float* __restrict__ Wq, const float* __restrict__ Wk,
               const float* __restrict__ Wv, const float* __restrict__ Wo,
               const float* __restrict__ bq, const float* __restrict__ bk,
               const float* __restrict__ bv,
               u16* __restrict__ xb, u16* __restrict__ wqkv, u16* __restrict__ wob,
               float* __restrict__ bcat)
{
    int bx = blockIdx.x, tid = threadIdx.x;
    if (bx < XBLK) {
        int i = (bx * 256 + tid) * 4;
        float4 v = *(const float4*)(x + i);
        ushort4 o;
        o.x = f2b(v.x); o.y = f2b(v.y); o.z = f2b(v.z); o.w = f2b(v.w);
        *(ushort4*)(xb + i) = o;
    } else if (bx < XBLK + 4*WBLK) {
        int z = (bx - XBLK) / WBLK;
        int blk = (bx - XBLK) % WBLK;
        const float* src = (z == 0) ? Wq : (z == 1) ? Wk : (z == 2) ? Wv : Wo;
        u16* dst = (z == 3) ? wob : wqkv + (size_t)z * CDIM * CDIM;
        int i = (blk * 256 + tid) * 4;
        float4 v = *(const float4*)(src + i);
        ushort4 o;
        o.x = f2b(v.x); o.y = f2b(v.y); o.z = f2b(v.z); o.w = f2b(v.w);
        *(ushort4*)(dst + i) = o;
    } else {
        int i = (bx - XBLK - 4*WBLK) * 256 + tid;
        if (i < CDIM) bcat[i] = bq[i];
        else if (i < 2*CDIM) bcat[i] = bk[i - CDIM];
        else if (i < 3*CDIM) bcat[i] = bv[i - 2*CDIM];
    }
}

// ---------------------------------------------------------------------------
// bf16 GEMM: Y[m,n] = (sum_k A[m,k]*B[n,k] + bias[n]) * (n<qn ? qscale : 1)
// 128x128 tile, BK=32, 4 waves (2x2 of 64x64), 16x16x32 MFMA, XOR-swizzled
// global_load_lds staging, DOUBLE-BUFFERED at 32KB LDS -> 4-5 blocks/CU.
// Round-9 evidence: counted-vmcnt tri-buffer was null (T4 needs 8-phase;
// regime gate) and its swizzle c^(row&3) had period-4 bank spans -> 3.54M
// conflicts. Corrected swizzle: swz(row) = (row>>1)&3 gives bank-span
// 4*(m&1) + quad^((m>>1)&3) — full period 8, 2 lanes/span (free), the same
// signature as the proven conflict-free BK=64 layout. Round 8 showed
// occupancy is the dominant overlap mechanism here; BK=32 dbuf maximizes
// resident blocks with the known-good 1-barrier/step sync structure.
// XCD-aware block swizzle (T1): per-XCD working set ~5MB ~= one L2.
// VFRAG=1: tiles with n0>=1536 (the V columns of the QKV GEMM) are written
// as pre-packed PV fragments into Vt instead of rows into Y.
// Fragment layout (matched to 16x16x32 PV MFMA, semantic k within a 32-key
// block: k(quad,j) = j<4 ? 4*quad+j : 16+4*quad+(j-4)):
//   epilogue element (i,j',r): seq s64 = i*16+quad*4+r -> t=i>>1,
//   word wj = 4*(i&1)+r, fragment lane = quad*16 + l15, jd = j'.
//   Vt[(bh*32+kt)*VTILE + ((t*4+jd)*64 + lane)*8 + 4*(i&1) + r]
// ---------------------------------------------------------------------------
template<int OUTF32, int VFRAG>
__global__ __launch_bounds__(256)
void gemm_bf16(const u16* __restrict__ A, const u16* __restrict__ B,
               const float* __restrict__ bias, void* __restrict__ Y,
               u16* __restrict__ Vt,
               int N, int K, int qn, float qscale)
{
    __shared__ __align__(16) u16 As[2][128*32];
    __shared__ __align__(16) u16 Bs[2][128*32];
    const int tid = threadIdx.x;
    // ---- XCD swizzle: nwg % 8 == 0 for all launches (1152 / 384) ----
    const int nwg = gridDim.x * gridDim.y;
    const int fid = blockIdx.y * gridDim.x + blockIdx.x;
    const int swz = (fid & 7) * (nwg >> 3) + (fid >> 3);
    const int m0 = (swz / gridDim.x) * 128, n0 = (swz % gridDim.x) * 128;
    const int wid = tid >> 6, lane = tid & 63;
    const int wm = (wid & 1) * 64, wn = (wid >> 1) * 64;
    const int l15 = lane & 15, quad = lane >> 4;

    f32x4 acc[4][4];
    #pragma unroll
    for (int i = 0; i < 4; ++i)
        #pragma unroll
        for (int j = 0; j < 4; ++j)
            #pragma unroll
            for (int r = 0; r < 4; ++r) acc[i][j][r] = 0.f;

    // stage one BK=32 tile (8KB per array): 4 ASYNC16/thread
    auto stage = [&](int buf, int t) {
        int k0 = t * 32;
        #pragma unroll
        for (int r = 0; r < 2; ++r) {
            int li = r*256 + tid;
            int row = li >> 2, c = li & 3;
            int gc = c ^ ((row >> 1) & 3);
            ASYNC16(A + (size_t)(m0 + row) * K + k0 + gc*8, &As[buf][li*8]);
            ASYNC16(B + (size_t)(n0 + row) * K + k0 + gc*8, &Bs[buf][li*8]);
        }
    };

    const int NT = K / 32;                 // 24 for K=768
    stage(0, 0);
    __syncthreads();                       // drains prologue asyncs

    for (int t = 0; t < NT; ++t) {
        const int bufc = t & 1;
        if (t + 1 < NT) stage(bufc ^ 1, t + 1);   // overlap with MFMA below

        bf16x8 a[4], b[4];
        #pragma unroll
        for (int i = 0; i < 4; ++i) {
            int m = wm + i*16 + l15;
            int ca = quad ^ ((m >> 1) & 3);
            a[i] = *(const bf16x8*)&As[bufc][m*32 + ca*8];
            int n = wn + i*16 + l15;
            int cbx = quad ^ ((n >> 1) & 3);
            b[i] = *(const bf16x8*)&Bs[bufc][n*32 + cbx*8];
        }
        #pragma unroll
        for (int i = 0; i < 4; ++i)
            #pragma unroll
            for (int j = 0; j < 4; ++j)
                acc[i][j] = __builtin_amdgcn_mfma_f32_16x16x32_bf16(a[i], b[j], acc[i][j], 0, 0, 0);

        __syncthreads();   // drains next-tile asyncs; protects buffer reuse
    }

    if (VFRAG && n0 >= 2*CDIM) {
        // ---- V tile: write PV 16x16x32 B-fragments straight to Vt ----
        #pragma unroll
        for (int i = 0; i < 4; ++i) {
            int gm = m0 + wm + i*16 + quad*4;      // seq base for r=0..3
            int bb = gm >> 11;                     // batch
            int kt = (gm & 2047) >> 6;             // 64-key tile
            int t  = i >> 1;                       // 32-key block within tile
            int wj = (i & 1) * 4;                  // word offset in fragment
            #pragma unroll
            for (int j = 0; j < 4; ++j) {
                int gn = n0 + wn + j*16 + l15;
                float bv = bias[gn];
                int d = gn - 2*CDIM;
                int h = d >> 6, jd = (d & 63) >> 4;  // jd == j
                int bh = bb * NHEADS + h;
                u32 p0 = prnd(acc[i][j][0] + bv);
                u32 p1 = prnd(acc[i][j][1] + bv);
                u32 p2 = prnd(acc[i][j][2] + bv);
                u32 p3 = prnd(acc[i][j][3] + bv);
                uint2 st;
                st.x = __builtin_amdgcn_perm(p1, p0, 0x07060302u);
                st.y = __builtin_amdgcn_perm(p3, p2, 0x07060302u);
                *(uint2*)(Vt + ((size_t)(bh*32 + kt))*VTILE
                             + (size_t)((t*4 + jd)*64 + lane)*8 + wj) = st;
            }
        }
    } else {
        #pragma unroll
        for (int i = 0; i < 4; ++i) {
            #pragma unroll
            for (int j = 0; j < 4; ++j) {
                int gn = n0 + wn + j*16 + l15;
                float bv = bias[gn];
                float sc = (gn < qn) ? qscale : 1.0f;
                #pragma unroll
                for (int r = 0; r < 4; ++r) {
                    int gm = m0 + wm + i*16 + quad*4 + r;
                    float v = (acc[i][j][r] + bv) * sc;
                    if (OUTF32) ((float*)Y)[(size_t)gm * N + gn] = v;
                    else        ((u16*)Y)[(size_t)gm * N + gn] = f2b(v);
                }
            }
        }
    }
}

// ---------------------------------------------------------------------------
// MFMA flash attention (round-7 version — best measured: 61.5us, 3 blocks/CU;
// the T15 cross-tile pipeline regressed by dropping occupancy). S^T = K.Q^T,
// exp2 in-register (log2e folded into q upstream), P packed via prnd+v_perm
// into bf16x8 A-fragments with consistent semantic k (matches the V fragment
// layout from the QKV GEMM epilogue -> PV is full-rate 16x16x32 MFMA, no
// cross-lane shuffle). Zero-C first S-half. V split: t=0 half LDS-staged
// (dbuf), t=1 half direct-global (pipe balance, rounds 2/4). K LDS-staged
// dbuf XOR-swizzled. 1 barrier/tile. setprio(1) around MFMA clusters (T5).
// XCD swizzle (T1): FETCH 104->18.5MB.
// ---------------------------------------------------------------------------
__global__ __launch_bounds__(256, 3)
void attn_mfma(const u16* __restrict__ QK, const u16* __restrict__ Vt,
               u16* __restrict__ Oa)
{
    __shared__ __align__(16) u16 Ks[2][64*64];
    __shared__ __align__(16) u16 Vls[2][2048];   // t=0 fragment half (4 KB)

    const int tid = threadIdx.x;
    const int wid = tid >> 6, lane = tid & 63;
    const int l15 = lane & 15, quad = lane >> 4;
    // ---- XCD swizzle: nwg = 16*48 = 768, 96 logical blocks per XCD ----
    const int fid = blockIdx.y * gridDim.x + blockIdx.x;
    const int swz = (fid & 7) * 96 + (fid >> 3);
    const int qt = swz & 15, bh = swz >> 4;
    const int b = bh / NHEADS, h = bh % NHEADS;

    const u16* Qg  = QK + ((size_t)(b*SEQ + qt*QROWS)) * NQKV + h*HDIM;
    const u16* Kg0 = QK + ((size_t)(b*SEQ)) * NQKV + CDIM + h*HDIM;
    const u16* Vg  = Vt + (size_t)bh * 32 * VTILE;   // + kt*VTILE per tile

    // ---- prologue: stage K0 + V0(t=0 half); Q frags straight to registers ----
    #pragma unroll
    for (int r = 0; r < 2; ++r) {
        int li = r*256 + tid, row = li >> 3, c = li & 7, gc = c ^ (row & 7);
        ASYNC16(Kg0 + (size_t)row * NQKV + gc*8, &Ks[0][li*8]);
    }
    ASYNC16(Vg + tid*8, &Vls[0][tid*8]);

    // Q as B-operand of 16x16x32: B[n=l15][k=quad*8+jj]
    bf16x8 qf[2][2];
    #pragma unroll
    for (int mb = 0; mb < 2; ++mb)
        #pragma unroll
        for (int kk = 0; kk < 2; ++kk)
            qf[mb][kk] = *(const bf16x8*)(Qg + (size_t)(wid*32 + mb*16 + l15) * NQKV + kk*32 + quad*8);

    const bf16x8 ONES8 = { (short)0x3F80, (short)0x3F80, (short)0x3F80, (short)0x3F80,
                           (short)0x3F80, (short)0x3F80, (short)0x3F80, (short)0x3F80 };
    const f32x4 ZERO4 = { 0.f, 0.f, 0.f, 0.f };

    f32x4 o[2][4];
    #pragma unroll
    for (int mb = 0; mb < 2; ++mb)
        #pragma unroll
        for (int j = 0; j < 4; ++j)
            #pragma unroll
            for (int r = 0; r < 4; ++r) o[mb][j][r] = 0.f;
    f32x4 ll[2];
    #pragma unroll
    for (int mb = 0; mb < 2; ++mb)
        #pragma unroll
        for (int r = 0; r < 4; ++r) ll[mb][r] = 0.f;

    __syncthreads();

    auto body = [&](int kt, int cbuf, int nbuf) {
        if (kt + 1 < SEQ/64) {
            #pragma unroll
            for (int r = 0; r < 2; ++r) {
                int li = r*256 + tid, row = li >> 3, c = li & 7, gc = c ^ (row & 7);
                ASYNC16(Kg0 + (size_t)((kt+1)*64 + row) * NQKV + gc*8, &Ks[nbuf][li*8]);
            }
            ASYNC16(Vg + (size_t)(kt+1) * VTILE + tid*8, &Vls[nbuf][tid*8]);
        }

        // ---- V fragments: t=0 from LDS (2-way alias, conflict-free),
        //      t=1 direct from global (coalesced 16B/lane, L2-hit).
        bf16x8 vf[2][4];
        #pragma unroll
        for (int jd = 0; jd < 4; ++jd) {
            vf[0][jd] = *(const bf16x8*)&Vls[cbuf][(size_t)(jd*64 + lane)*8];
            vf[1][jd] = *(const bf16x8*)(Vg + (size_t)kt * VTILE
                                         + (size_t)((4 + jd)*64 + lane)*8);
        }

        // ---- S^T = K.Q^T : s[mb][j][r] = S[q=mb-block+l15][k=j*16+quad*4+r]
        // kk=0 with zero C-operand (no accumulator init), kk=1 accumulates.
        f32x4 s[2][4];
        __builtin_amdgcn_s_setprio(1);
        #pragma unroll
        for (int j = 0; j < 4; ++j) {
            int kr = j*16 + l15;
            int ck = quad ^ (kr & 7);
            bf16x8 ak = *(const bf16x8*)&Ks[cbuf][kr*64 + ck*8];
            #pragma unroll
            for (int mb = 0; mb < 2; ++mb)
                s[mb][j] = __builtin_amdgcn_mfma_f32_16x16x32_bf16(ak, qf[mb][0], ZERO4, 0, 0, 0);
        }
        #pragma unroll
        for (int j = 0; j < 4; ++j) {
            int kr = j*16 + l15;
            int ck = (4 + quad) ^ (kr & 7);
            bf16x8 ak = *(const bf16x8*)&Ks[cbuf][kr*64 + ck*8];
            #pragma unroll
            for (int mb = 0; mb < 2; ++mb)
                s[mb][j] = __builtin_amdgcn_mfma_f32_16x16x32_bf16(ak, qf[mb][1], s[mb][j], 0, 0, 0);
        }
        __builtin_amdgcn_s_setprio(0);

        // ---- p = 2^s in-register; pack to 16x16x32 A-fragments (prnd+perm) ----
        bf16x8 pf[2][2];
        #pragma unroll
        for (int mb = 0; mb < 2; ++mb)
            #pragma unroll
            for (int t = 0; t < 2; ++t) {
                u32 a0 = prnd(__builtin_amdgcn_exp2f(s[mb][2*t][0]));
                u32 a1 = prnd(__builtin_amdgcn_exp2f(s[mb][2*t][1]));
                u32 a2 = prnd(__builtin_amdgcn_exp2f(s[mb][2*t][2]));
                u32 a3 = prnd(__builtin_amdgcn_exp2f(s[mb][2*t][3]));
                u32 b0 = prnd(__builtin_amdgcn_exp2f(s[mb][2*t+1][0]));
                u32 b1 = prnd(__builtin_amdgcn_exp2f(s[mb][2*t+1][1]));
                u32 b2 = prnd(__builtin_amdgcn_exp2f(s[mb][2*t+1][2]));
                u32 b3 = prnd(__builtin_amdgcn_exp2f(s[mb][2*t+1][3]));
                union { uint4 u; bf16x8 v; } cst;
                cst.u.x = __builtin_amdgcn_perm(a1, a0, 0x07060302u);
                cst.u.y = __builtin_amdgcn_perm(a3, a2, 0x07060302u);
                cst.u.z = __builtin_amdgcn_perm(b1, b0, 0x07060302u);
                cst.u.w = __builtin_amdgcn_perm(b3, b2, 0x07060302u);
                pf[mb][t] = cst.v;
            }

        // ---- O += P V ; l += P . 1 ----
        __builtin_amdgcn_s_setprio(1);
        #pragma unroll
        for (int t = 0; t < 2; ++t) {
            #pragma unroll
            for (int jd = 0; jd < 4; ++jd) {
                #pragma unroll
                for (int mb = 0; mb < 2; ++mb)
                    o[mb][jd] = __builtin_amdgcn_mfma_f32_16x16x32_bf16(pf[mb][t], vf[t][jd], o[mb][jd], 0, 0, 0);
            }
            #pragma unroll
            for (int mb = 0; mb < 2; ++mb)
                ll[mb] = __builtin_amdgcn_mfma_f32_16x16x32_bf16(pf[mb][t], ONES8, ll[mb], 0, 0, 0);
        }
        __builtin_amdgcn_s_setprio(0);
        __syncthreads();   // drains next-tile asyncs; protects buffer reuse
    };

    for (int kt = 0; kt < SEQ/64; kt += 2) {
        body(kt,   0, 1);
        body(kt+1, 1, 0);
    }

    // ---- epilogue: O rows q = quad*4+r, cols d = jd*16+l15; l same layout ----
    u16* Og = Oa + ((size_t)(b*SEQ + qt*QROWS)) * CDIM + h*HDIM;
    #pragma unroll
    for (int mb = 0; mb < 2; ++mb) {
        #pragma unroll
        for (int r = 0; r < 4; ++r) {
            float inv = 1.f / ll[mb][r];
            int row = wid*32 + mb*16 + quad*4 + r;
            #pragma unroll
            for (int jd = 0; jd < 4; ++jd)
                Og[(size_t)row * CDIM + jd*16 + l15] = f2b(o[mb][jd][r] * inv);
        }
    }
}

// ---------------------------------------------------------------------------
extern "C" void kernel_launch(void* const* d_in, const int* in_sizes, int n_in,
                              void* d_out, int out_size, void* d_ws, size_t ws_size,
                              hipStream_t stream)
{
    const float* x  = (const float*)d_in[0];
    const float* Wq = (const float*)d_in[1];
    const float* bq = (const float*)d_in[2];
    const float* Wk = (const float*)d_in[3];
    const float* bk = (const float*)d_in[4];
    const float* Wv = (const float*)d_in[5];
    const float* bv = (const float*)d_in[6];
    const float* Wo = (const float*)d_in[7];
    const float* bo = (const float*)d_in[8];

    unsigned char* ws = (unsigned char*)d_ws;
    u16* xb   = (u16*)ws;  ws += (size_t)MTOT * CDIM * 2;
    u16* wqkv = (u16*)ws;  ws += (size_t)NQKV * CDIM * 2;
    u16* wob  = (u16*)ws;  ws += (size_t)CDIM * CDIM * 2;
    float* bcat = (float*)ws; ws += (size_t)NQKV * 4;
    u16* qkv  = (u16*)ws;  ws += (size_t)MTOT * NQKV * 2;
    u16* vt   = (u16*)ws;  ws += (size_t)BATCH*NHEADS*32*VTILE * 2;
    u16* ao   = (u16*)ws;

    prep_kern<<<XBLK + 4*WBLK + 9, 256, 0, stream>>>(x, Wq, Wk, Wv, Wo, bq, bk, bv,
                                                     xb, wqkv, wob, bcat);

    // q pre-scaled by log2(e)/sqrt(HDIM) so softmax is a bare exp2
    gemm_bf16<0,1><<<dim3(NQKV/128, MTOT/128), 256, 0, stream>>>(xb, wqkv, bcat, qkv, vt, NQKV, CDIM, CDIM, 0.18033688f);
    attn_mfma<<<dim3(SEQ/QROWS, BATCH*NHEADS), 256, 0, stream>>>(qkv, vt, ao);
    gemm_bf16<1,0><<<dim3(CDIM/128, MTOT/128), 256, 0, stream>>>(ao, wob, bo, (float*)d_out, nullptr, CDIM, CDIM, 0, 1.0f);
}

// Round 11
// 210.164 us; speedup vs baseline: 1.0818x; 1.0736x over previous
//
#include <hip/hip_runtime.h>
#include <math.h>

#define CDIM 768
#define NHEADS 12
#define HDIM 64
#define BATCH 4
#define SEQ 2048
#define MTOT (BATCH*SEQ)     // 8192
#define NQKV (3*CDIM)        // 2304
#define QROWS 128            // Q rows per attention block
#define VTILE 4096           // u16 elements per fragmented V tile (2 blk * 4 jd * 64 lane * 8)

typedef __attribute__((ext_vector_type(8))) short bf16x8;
typedef __attribute__((ext_vector_type(4))) float f32x4;
typedef unsigned short u16;
typedef unsigned int u32;

// async global->LDS, 16B per lane. LDS dest must be wave-uniform base + lane*16
// (global source address is per-lane free-form).
#define ASYNC16(gsrc, ldst) \
  __builtin_amdgcn_global_load_lds((const __attribute__((address_space(1))) void*)(gsrc), \
                                   (__attribute__((address_space(3))) void*)(ldst), 16, 0, 0)

// RNE fp32->bf16 (finite inputs only)
__device__ inline u16 f2b(float x) {
    unsigned int u = __float_as_uint(x);
    return (u16)((u + 0x7fffu + ((u >> 16) & 1u)) >> 16);
}
// rounding-biased uint for pack: hi16(u+0x8000) = round-half-up-in-magnitude bf16
__device__ inline u32 prnd(float x) { return __float_as_uint(x) + 0x8000u; }

// ---------------------------------------------------------------------------
// Fused prologue: x cast (6144 blocks) + 4 weight casts (4*576) + bias concat (9)
// ---------------------------------------------------------------------------
#define XBLK (MTOT*CDIM/1024)        // 6144
#define WBLK (CDIM*CDIM/1024)        // 576
__global__ __launch_bounds__(256)
void prep_kern(const float* __restrict__ x,
               const float* __restrict__ Wq, const float* __restrict__ Wk,
               const float* __restrict__ Wv, const float* __restrict__ Wo,
               const float* __restrict__ bq, const float* __restrict__ bk,
               const float* __restrict__ bv,
               u16* __restrict__ xb, u16* __restrict__ wqkv, u16* __restrict__ wob,
               float* __restrict__ bcat)
{
    int bx = blockIdx.x, tid = threadIdx.x;
    if (bx < XBLK) {
        int i = (bx * 256 + tid) * 4;
        float4 v = *(const float4*)(x + i);
        ushort4 o;
        o.x = f2b(v.x); o.y = f2b(v.y); o.z = f2b(v.z); o.w = f2b(v.w);
        *(ushort4*)(xb + i) = o;
    } else if (bx < XBLK + 4*WBLK) {
        int z = (bx - XBLK) / WBLK;
        int blk = (bx - XBLK) % WBLK;
        const float* src = (z == 0) ? Wq : (z == 1) ? Wk : (z == 2) ? Wv : Wo;
        u16* dst = (z == 3) ? wob : wqkv + (size_t)z * CDIM * CDIM;
        int i = (blk * 256 + tid) * 4;
        float4 v = *(const float4*)(src + i);
        ushort4 o;
        o.x = f2b(v.x); o.y = f2b(v.y); o.z = f2b(v.z); o.w = f2b(v.w);
        *(ushort4*)(dst + i) = o;
    } else {
        int i = (bx - XBLK - 4*WBLK) * 256 + tid;
        if (i < CDIM) bcat[i] = bq[i];
        else if (i < 2*CDIM) bcat[i] = bk[i - CDIM];
        else if (i < 3*CDIM) bcat[i] = bv[i - 2*CDIM];
    }
}

// ---------------------------------------------------------------------------
// bf16 GEMM: Y[m,n] = (sum_k A[m,k]*B[n,k] + bias[n]) * (n<qn ? qscale : 1)
// 128x128 tile, BK=64, 4 waves (2x2 of 64x64), 16x16x32 MFMA, XOR-swizzled
// global_load_lds staging, DOUBLE-BUFFERED (T3 minimum-2-phase).
// Design-space verdict (rounds 5/6/9/10): single-buf 65.9us; BK=64 dbuf
// <62us (BEST, total 211.3); BK=32 tri-buf+counted-vmcnt 65.3 (T4 null on
// 2-phase, regime gate) ; BK=32 dbuf worse by ~14us total (barrier count
// doubles, compute window per barrier too short). Occupancy (r8) and
// barrier amortization (r10) are both first-order; BK=64 dbuf is the
// measured optimum of the 2-phase family. Next structural step would be
// the 256^2 8-phase template, not parameter tweaks.
// XCD-aware block swizzle (T1): FETCH 70.6MB -> L2-local panels.
// VFRAG=1: tiles with n0>=1536 (the V columns of the QKV GEMM) are written
// as pre-packed PV fragments into Vt instead of rows into Y.
// Fragment layout (matched to 16x16x32 PV MFMA, semantic k within a 32-key
// block: k(quad,j) = j<4 ? 4*quad+j : 16+4*quad+(j-4)):
//   epilogue element (i,j',r): seq s64 = i*16+quad*4+r -> t=i>>1,
//   word wj = 4*(i&1)+r, fragment lane = quad*16 + l15, jd = j'.
//   Vt[(bh*32+kt)*VTILE + ((t*4+jd)*64 + lane)*8 + 4*(i&1) + r]
// ---------------------------------------------------------------------------
template<int OUTF32, int VFRAG>
__global__ __launch_bounds__(256)
void gemm_bf16(const u16* __restrict__ A, const u16* __restrict__ B,
               const float* __restrict__ bias, void* __restrict__ Y,
               u16* __restrict__ Vt,
               int N, int K, int qn, float qscale)
{
    __shared__ __align__(16) u16 As[2][128*64];
    __shared__ __align__(16) u16 Bs[2][128*64];
    const int tid = threadIdx.x;
    // ---- XCD swizzle: nwg % 8 == 0 for all launches (1152 / 384) ----
    const int nwg = gridDim.x * gridDim.y;
    const int fid = blockIdx.y * gridDim.x + blockIdx.x;
    const int swz = (fid & 7) * (nwg >> 3) + (fid >> 3);
    const int m0 = (swz / gridDim.x) * 128, n0 = (swz % gridDim.x) * 128;
    const int wid = tid >> 6, lane = tid & 63;
    const int wm = (wid & 1) * 64, wn = (wid >> 1) * 64;
    const int l15 = lane & 15, quad = lane >> 4;

    f32x4 acc[4][4];
    #pragma unroll
    for (int i = 0; i < 4; ++i)
        #pragma unroll
        for (int j = 0; j < 4; ++j)
            #pragma unroll
            for (int r = 0; r < 4; ++r) acc[i][j][r] = 0.f;

    auto stage = [&](int buf, int t) {
        int k0 = t * 64;
        #pragma unroll
        for (int r = 0; r < 4; ++r) {
            int li = r*256 + tid;
            int row = li >> 3, c = li & 7;
            int gc = c ^ (row & 7);
            ASYNC16(A + (size_t)(m0 + row) * K + k0 + gc*8, &As[buf][li*8]);
            ASYNC16(B + (size_t)(n0 + row) * K + k0 + gc*8, &Bs[buf][li*8]);
        }
    };

    const int NT = K / 64;
    stage(0, 0);
    __syncthreads();                       // drains prologue asyncs

    for (int t = 0; t < NT; ++t) {
        const int bufc = t & 1;
        if (t + 1 < NT) stage(bufc ^ 1, t + 1);   // overlap with MFMA below
        #pragma unroll
        for (int kk = 0; kk < 2; ++kk) {
            bf16x8 a[4], b[4];
            #pragma unroll
            for (int i = 0; i < 4; ++i) {
                int m = wm + i*16 + l15;
                int ca = (kk*4 + quad) ^ (m & 7);
                a[i] = *(const bf16x8*)&As[bufc][m*64 + ca*8];
                int n = wn + i*16 + l15;
                int cbx = (kk*4 + quad) ^ (n & 7);
                b[i] = *(const bf16x8*)&Bs[bufc][n*64 + cbx*8];
            }
            #pragma unroll
            for (int i = 0; i < 4; ++i)
                #pragma unroll
                for (int j = 0; j < 4; ++j)
                    acc[i][j] = __builtin_amdgcn_mfma_f32_16x16x32_bf16(a[i], b[j], acc[i][j], 0, 0, 0);
        }
        __syncthreads();   // drains next-tile asyncs; protects buffer reuse
    }

    if (VFRAG && n0 >= 2*CDIM) {
        // ---- V tile: write PV 16x16x32 B-fragments straight to Vt ----
        #pragma unroll
        for (int i = 0; i < 4; ++i) {
            int gm = m0 + wm + i*16 + quad*4;      // seq base for r=0..3
            int bb = gm >> 11;                     // batch
            int kt = (gm & 2047) >> 6;             // 64-key tile
            int t  = i >> 1;                       // 32-key block within tile
            int wj = (i & 1) * 4;                  // word offset in fragment
            #pragma unroll
            for (int j = 0; j < 4; ++j) {
                int gn = n0 + wn + j*16 + l15;
                float bv = bias[gn];
                int d = gn - 2*CDIM;
                int h = d >> 6, jd = (d & 63) >> 4;  // jd == j
                int bh = bb * NHEADS + h;
                u32 p0 = prnd(acc[i][j][0] + bv);
                u32 p1 = prnd(acc[i][j][1] + bv);
                u32 p2 = prnd(acc[i][j][2] + bv);
                u32 p3 = prnd(acc[i][j][3] + bv);
                uint2 st;
                st.x = __builtin_amdgcn_perm(p1, p0, 0x07060302u);
                st.y = __builtin_amdgcn_perm(p3, p2, 0x07060302u);
                *(uint2*)(Vt + ((size_t)(bh*32 + kt))*VTILE
                             + (size_t)((t*4 + jd)*64 + lane)*8 + wj) = st;
            }
        }
    } else {
        #pragma unroll
        for (int i = 0; i < 4; ++i) {
            #pragma unroll
            for (int j = 0; j < 4; ++j) {
                int gn = n0 + wn + j*16 + l15;
                float bv = bias[gn];
                float sc = (gn < qn) ? qscale : 1.0f;
                #pragma unroll
                for (int r = 0; r < 4; ++r) {
                    int gm = m0 + wm + i*16 + quad*4 + r;
                    float v = (acc[i][j][r] + bv) * sc;
                    if (OUTF32) ((float*)Y)[(size_t)gm * N + gn] = v;
                    else        ((u16*)Y)[(size_t)gm * N + gn] = f2b(v);
                }
            }
        }
    }
}

// ---------------------------------------------------------------------------
// MFMA flash attention (round-7 version — best measured: 61.4us, FETCH
// 18.5MB, 0 conflicts; the T15 cross-tile pipeline regressed 61.5->79.5 by
// dropping occupancy 3->2 blocks/CU — occupancy is the dominant overlap
// mechanism here). S^T = K.Q^T, exp2 in-register (log2e folded into q
// upstream), P packed via prnd+v_perm into bf16x8 A-fragments with
// consistent semantic k (matches the V fragment layout from the QKV GEMM
// epilogue -> PV is full-rate 16x16x32 MFMA, no cross-lane shuffle).
// Zero-C first S-half. V split: t=0 half LDS-staged (dbuf), t=1 half
// direct-global (pipe balance, rounds 2/4). K LDS-staged dbuf XOR-swizzled.
// 1 barrier/tile. setprio(1) around MFMA clusters (T5). XCD swizzle (T1).
// ---------------------------------------------------------------------------
__global__ __launch_bounds__(256, 3)
void attn_mfma(const u16* __restrict__ QK, const u16* __restrict__ Vt,
               u16* __restrict__ Oa)
{
    __shared__ __align__(16) u16 Ks[2][64*64];
    __shared__ __align__(16) u16 Vls[2][2048];   // t=0 fragment half (4 KB)

    const int tid = threadIdx.x;
    const int wid = tid >> 6, lane = tid & 63;
    const int l15 = lane & 15, quad = lane >> 4;
    // ---- XCD swizzle: nwg = 16*48 = 768, 96 logical blocks per XCD ----
    const int fid = blockIdx.y * gridDim.x + blockIdx.x;
    const int swz = (fid & 7) * 96 + (fid >> 3);
    const int qt = swz & 15, bh = swz >> 4;
    const int b = bh / NHEADS, h = bh % NHEADS;

    const u16* Qg  = QK + ((size_t)(b*SEQ + qt*QROWS)) * NQKV + h*HDIM;
    const u16* Kg0 = QK + ((size_t)(b*SEQ)) * NQKV + CDIM + h*HDIM;
    const u16* Vg  = Vt + (size_t)bh * 32 * VTILE;   // + kt*VTILE per tile

    // ---- prologue: stage K0 + V0(t=0 half); Q frags straight to registers ----
    #pragma unroll
    for (int r = 0; r < 2; ++r) {
        int li = r*256 + tid, row = li >> 3, c = li & 7, gc = c ^ (row & 7);
        ASYNC16(Kg0 + (size_t)row * NQKV + gc*8, &Ks[0][li*8]);
    }
    ASYNC16(Vg + tid*8, &Vls[0][tid*8]);

    // Q as B-operand of 16x16x32: B[n=l15][k=quad*8+jj]
    bf16x8 qf[2][2];
    #pragma unroll
    for (int mb = 0; mb < 2; ++mb)
        #pragma unroll
        for (int kk = 0; kk < 2; ++kk)
            qf[mb][kk] = *(const bf16x8*)(Qg + (size_t)(wid*32 + mb*16 + l15) * NQKV + kk*32 + quad*8);

    const bf16x8 ONES8 = { (short)0x3F80, (short)0x3F80, (short)0x3F80, (short)0x3F80,
                           (short)0x3F80, (short)0x3F80, (short)0x3F80, (short)0x3F80 };
    const f32x4 ZERO4 = { 0.f, 0.f, 0.f, 0.f };

    f32x4 o[2][4];
    #pragma unroll
    for (int mb = 0; mb < 2; ++mb)
        #pragma unroll
        for (int j = 0; j < 4; ++j)
            #pragma unroll
            for (int r = 0; r < 4; ++r) o[mb][j][r] = 0.f;
    f32x4 ll[2];
    #pragma unroll
    for (int mb = 0; mb < 2; ++mb)
        #pragma unroll
        for (int r = 0; r < 4; ++r) ll[mb][r] = 0.f;

    __syncthreads();

    auto body = [&](int kt, int cbuf, int nbuf) {
        if (kt + 1 < SEQ/64) {
            #pragma unroll
            for (int r = 0; r < 2; ++r) {
                int li = r*256 + tid, row = li >> 3, c = li & 7, gc = c ^ (row & 7);
                ASYNC16(Kg0 + (size_t)((kt+1)*64 + row) * NQKV + gc*8, &Ks[nbuf][li*8]);
            }
            ASYNC16(Vg + (size_t)(kt+1) * VTILE + tid*8, &Vls[nbuf][tid*8]);
        }

        // ---- V fragments: t=0 from LDS (2-way alias, conflict-free),
        //      t=1 direct from global (coalesced 16B/lane, L2-hit).
        bf16x8 vf[2][4];
        #pragma unroll
        for (int jd = 0; jd < 4; ++jd) {
            vf[0][jd] = *(const bf16x8*)&Vls[cbuf][(size_t)(jd*64 + lane)*8];
            vf[1][jd] = *(const bf16x8*)(Vg + (size_t)kt * VTILE
                                         + (size_t)((4 + jd)*64 + lane)*8);
        }

        // ---- S^T = K.Q^T : s[mb][j][r] = S[q=mb-block+l15][k=j*16+quad*4+r]
        // kk=0 with zero C-operand (no accumulator init), kk=1 accumulates.
        f32x4 s[2][4];
        __builtin_amdgcn_s_setprio(1);
        #pragma unroll
        for (int j = 0; j < 4; ++j) {
            int kr = j*16 + l15;
            int ck = quad ^ (kr & 7);
            bf16x8 ak = *(const bf16x8*)&Ks[cbuf][kr*64 + ck*8];
            #pragma unroll
            for (int mb = 0; mb < 2; ++mb)
                s[mb][j] = __builtin_amdgcn_mfma_f32_16x16x32_bf16(ak, qf[mb][0], ZERO4, 0, 0, 0);
        }
        #pragma unroll
        for (int j = 0; j < 4; ++j) {
            int kr = j*16 + l15;
            int ck = (4 + quad) ^ (kr & 7);
            bf16x8 ak = *(const bf16x8*)&Ks[cbuf][kr*64 + ck*8];
            #pragma unroll
            for (int mb = 0; mb < 2; ++mb)
                s[mb][j] = __builtin_amdgcn_mfma_f32_16x16x32_bf16(ak, qf[mb][1], s[mb][j], 0, 0, 0);
        }
        __builtin_amdgcn_s_setprio(0);

        // ---- p = 2^s in-register; pack to 16x16x32 A-fragments (prnd+perm) ----
        bf16x8 pf[2][2];
        #pragma unroll
        for (int mb = 0; mb < 2; ++mb)
            #pragma unroll
            for (int t = 0; t < 2; ++t) {
                u32 a0 = prnd(__builtin_amdgcn_exp2f(s[mb][2*t][0]));
                u32 a1 = prnd(__builtin_amdgcn_exp2f(s[mb][2*t][1]));
                u32 a2 = prnd(__builtin_amdgcn_exp2f(s[mb][2*t][2]));
                u32 a3 = prnd(__builtin_amdgcn_exp2f(s[mb][2*t][3]));
                u32 b0 = prnd(__builtin_amdgcn_exp2f(s[mb][2*t+1][0]));
                u32 b1 = prnd(__builtin_amdgcn_exp2f(s[mb][2*t+1][1]));
                u32 b2 = prnd(__builtin_amdgcn_exp2f(s[mb][2*t+1][2]));
                u32 b3 = prnd(__builtin_amdgcn_exp2f(s[mb][2*t+1][3]));
                union { uint4 u; bf16x8 v; } cst;
                cst.u.x = __builtin_amdgcn_perm(a1, a0, 0x07060302u);
                cst.u.y = __builtin_amdgcn_perm(a3, a2, 0x07060302u);
                cst.u.z = __builtin_amdgcn_perm(b1, b0, 0x07060302u);
                cst.u.w = __builtin_amdgcn_perm(b3, b2, 0x07060302u);
                pf[mb][t] = cst.v;
            }

        // ---- O += P V ; l += P . 1 ----
        __builtin_amdgcn_s_setprio(1);
        #pragma unroll
        for (int t = 0; t < 2; ++t) {
            #pragma unroll
            for (int jd = 0; jd < 4; ++jd) {
                #pragma unroll
                for (int mb = 0; mb < 2; ++mb)
                    o[mb][jd] = __builtin_amdgcn_mfma_f32_16x16x32_bf16(pf[mb][t], vf[t][jd], o[mb][jd], 0, 0, 0);
            }
            #pragma unroll
            for (int mb = 0; mb < 2; ++mb)
                ll[mb] = __builtin_amdgcn_mfma_f32_16x16x32_bf16(pf[mb][t], ONES8, ll[mb], 0, 0, 0);
        }
        __builtin_amdgcn_s_setprio(0);
        __syncthreads();   // drains next-tile asyncs; protects buffer reuse
    };

    for (int kt = 0; kt < SEQ/64; kt += 2) {
        body(kt,   0, 1);
        body(kt+1, 1, 0);
    }

    // ---- epilogue: O rows q = quad*4+r, cols d = jd*16+l15; l same layout ----
    u16* Og = Oa + ((size_t)(b*SEQ + qt*QROWS)) * CDIM + h*HDIM;
    #pragma unroll
    for (int mb = 0; mb < 2; ++mb) {
        #pragma unroll
        for (int r = 0; r < 4; ++r) {
            float inv = 1.f / ll[mb][r];
            int row = wid*32 + mb*16 + quad*4 + r;
            #pragma unroll
            for (int jd = 0; jd < 4; ++jd)
                Og[(size_t)row * CDIM + jd*16 + l15] = f2b(o[mb][jd][r] * inv);
        }
    }
}

// ---------------------------------------------------------------------------
extern "C" void kernel_launch(void* const* d_in, const int* in_sizes, int n_in,
                              void* d_out, int out_size, void* d_ws, size_t ws_size,
                              hipStream_t stream)
{
    const float* x  = (const float*)d_in[0];
    const float* Wq = (const float*)d_in[1];
    const float* bq = (const float*)d_in[2];
    const float* Wk = (const float*)d_in[3];
    const float* bk = (const float*)d_in[4];
    const float* Wv = (const float*)d_in[5];
    const float* bv = (const float*)d_in[6];
    const float* Wo = (const float*)d_in[7];
    const float* bo = (const float*)d_in[8];

    unsigned char* ws = (unsigned char*)d_ws;
    u16* xb   = (u16*)ws;  ws += (size_t)MTOT * CDIM * 2;
    u16* wqkv = (u16*)ws;  ws += (size_t)NQKV * CDIM * 2;
    u16* wob  = (u16*)ws;  ws += (size_t)CDIM * CDIM * 2;
    float* bcat = (float*)ws; ws += (size_t)NQKV * 4;
    u16* qkv  = (u16*)ws;  ws += (size_t)MTOT * NQKV * 2;
    u16* vt   = (u16*)ws;  ws += (size_t)BATCH*NHEADS*32*VTILE * 2;
    u16* ao   = (u16*)ws;

    prep_kern<<<XBLK + 4*WBLK + 9, 256, 0, stream>>>(x, Wq, Wk, Wv, Wo, bq, bk, bv,
                                                     xb, wqkv, wob, bcat);

    // q pre-scaled by log2(e)/sqrt(HDIM) so softmax is a bare exp2
    gemm_bf16<0,1><<<dim3(NQKV/128, MTOT/128), 256, 0, stream>>>(xb, wqkv, bcat, qkv, vt, NQKV, CDIM, CDIM, 0.18033688f);
    attn_mfma<<<dim3(SEQ/QROWS, BATCH*NHEADS), 256, 0, stream>>>(qkv, vt, ao);
    gemm_bf16<1,0><<<dim3(CDIM/128, MTOT/128), 256, 0, stream>>>(ao, wob, bo, (float*)d_out, nullptr, CDIM, CDIM, 0, 1.0f);
}

// Round 12
// 207.964 us; speedup vs baseline: 1.0932x; 1.0106x over previous
//
#include <hip/hip_runtime.h>
#include <math.h>

#define CDIM 768
#define NHEADS 12
#define HDIM 64
#define BATCH 4
#define SEQ 2048
#define MTOT (BATCH*SEQ)     // 8192
#define NQKV (3*CDIM)        // 2304
#define QROWS 128            // Q rows per attention block
#define VTILE 4096           // u16 elements per fragmented V tile (2 blk * 4 jd * 64 lane * 8)

typedef __attribute__((ext_vector_type(8))) short bf16x8;
typedef __attribute__((ext_vector_type(4))) float f32x4;
typedef unsigned short u16;
typedef unsigned int u32;

// async global->LDS, 16B per lane. LDS dest must be wave-uniform base + lane*16
// (global source address is per-lane free-form).
#define ASYNC16(gsrc, ldst) \
  __builtin_amdgcn_global_load_lds((const __attribute__((address_space(1))) void*)(gsrc), \
                                   (__attribute__((address_space(3))) void*)(ldst), 16, 0, 0)

// RNE fp32->bf16 (finite inputs only)
__device__ inline u16 f2b(float x) {
    unsigned int u = __float_as_uint(x);
    return (u16)((u + 0x7fffu + ((u >> 16) & 1u)) >> 16);
}
// rounding-biased uint for pack: hi16(u+0x8000) = round-half-up-in-magnitude bf16
__device__ inline u32 prnd(float x) { return __float_as_uint(x) + 0x8000u; }

// ---------------------------------------------------------------------------
// Fused prologue: x cast (6144 blocks) + 4 weight casts (4*576) + bias concat (9)
// ---------------------------------------------------------------------------
#define XBLK (MTOT*CDIM/1024)        // 6144
#define WBLK (CDIM*CDIM/1024)        // 576
__global__ __launch_bounds__(256)
void prep_kern(const float* __restrict__ x,
               const float* __restrict__ Wq, const float* __restrict__ Wk,
               const float* __restrict__ Wv, const float* __restrict__ Wo,
               const float* __restrict__ bq, const float* __restrict__ bk,
               const float* __restrict__ bv,
               u16* __restrict__ xb, u16* __restrict__ wqkv, u16* __restrict__ wob,
               float* __restrict__ bcat)
{
    int bx = blockIdx.x, tid = threadIdx.x;
    if (bx < XBLK) {
        int i = (bx * 256 + tid) * 4;
        float4 v = *(const float4*)(x + i);
        ushort4 o;
        o.x = f2b(v.x); o.y = f2b(v.y); o.z = f2b(v.z); o.w = f2b(v.w);
        *(ushort4*)(xb + i) = o;
    } else if (bx < XBLK + 4*WBLK) {
        int z = (bx - XBLK) / WBLK;
        int blk = (bx - XBLK) % WBLK;
        const float* src = (z == 0) ? Wq : (z == 1) ? Wk : (z == 2) ? Wv : Wo;
        u16* dst = (z == 3) ? wob : wqkv + (size_t)z * CDIM * CDIM;
        int i = (blk * 256 + tid) * 4;
        float4 v = *(const float4*)(src + i);
        ushort4 o;
        o.x = f2b(v.x); o.y = f2b(v.y); o.z = f2b(v.z); o.w = f2b(v.w);
        *(ushort4*)(dst + i) = o;
    } else {
        int i = (bx - XBLK - 4*WBLK) * 256 + tid;
        if (i < CDIM) bcat[i] = bq[i];
        else if (i < 2*CDIM) bcat[i] = bk[i - CDIM];
        else if (i < 3*CDIM) bcat[i] = bv[i - 2*CDIM];
    }
}

// ---------------------------------------------------------------------------
// bf16 GEMM: Y[m,n] = (sum_k A[m,k]*B[n,k] + bias[n]) * (n<qn ? qscale : 1)
// 128x128 tile, BK=64, 4 waves (2x2 of 64x64), 16x16x32 MFMA, XOR-swizzled
// global_load_lds staging, DOUBLE-BUFFERED (T3 minimum-2-phase).
// Design-space verdict (rounds 5/6/9/10): single-buf 65.9us; BK=64 dbuf
// <62us (BEST, total 210-211); BK=32 tri-buf+counted-vmcnt 65.3 (T4 null on
// 2-phase, regime gate); BK=32 dbuf worse by ~14us total (barrier count
// doubles, compute window per barrier too short). Occupancy (r8) and
// barrier amortization (r10) are both first-order; BK=64 dbuf is the
// measured optimum of the 2-phase family.
// XCD-aware block swizzle (T1): FETCH 70.6MB -> L2-local panels.
// VFRAG=1: tiles with n0>=1536 (the V columns of the QKV GEMM) are written
// as pre-packed PV fragments into Vt instead of rows into Y.
// Fragment layout (matched to 16x16x32 PV MFMA, semantic k within a 32-key
// block: k(quad,j) = j<4 ? 4*quad+j : 16+4*quad+(j-4)):
//   epilogue element (i,j',r): seq s64 = i*16+quad*4+r -> t=i>>1,
//   word wj = 4*(i&1)+r, fragment lane = quad*16 + l15, jd = j'.
//   Vt[(bh*32+kt)*VTILE + ((t*4+jd)*64 + lane)*8 + 4*(i&1) + r]
// ---------------------------------------------------------------------------
template<int OUTF32, int VFRAG>
__global__ __launch_bounds__(256)
void gemm_bf16(const u16* __restrict__ A, const u16* __restrict__ B,
               const float* __restrict__ bias, void* __restrict__ Y,
               u16* __restrict__ Vt,
               int N, int K, int qn, float qscale)
{
    __shared__ __align__(16) u16 As[2][128*64];
    __shared__ __align__(16) u16 Bs[2][128*64];
    const int tid = threadIdx.x;
    // ---- XCD swizzle: nwg % 8 == 0 for all launches (1152 / 384) ----
    const int nwg = gridDim.x * gridDim.y;
    const int fid = blockIdx.y * gridDim.x + blockIdx.x;
    const int swz = (fid & 7) * (nwg >> 3) + (fid >> 3);
    const int m0 = (swz / gridDim.x) * 128, n0 = (swz % gridDim.x) * 128;
    const int wid = tid >> 6, lane = tid & 63;
    const int wm = (wid & 1) * 64, wn = (wid >> 1) * 64;
    const int l15 = lane & 15, quad = lane >> 4;

    f32x4 acc[4][4];
    #pragma unroll
    for (int i = 0; i < 4; ++i)
        #pragma unroll
        for (int j = 0; j < 4; ++j)
            #pragma unroll
            for (int r = 0; r < 4; ++r) acc[i][j][r] = 0.f;

    auto stage = [&](int buf, int t) {
        int k0 = t * 64;
        #pragma unroll
        for (int r = 0; r < 4; ++r) {
            int li = r*256 + tid;
            int row = li >> 3, c = li & 7;
            int gc = c ^ (row & 7);
            ASYNC16(A + (size_t)(m0 + row) * K + k0 + gc*8, &As[buf][li*8]);
            ASYNC16(B + (size_t)(n0 + row) * K + k0 + gc*8, &Bs[buf][li*8]);
        }
    };

    const int NT = K / 64;
    stage(0, 0);
    __syncthreads();                       // drains prologue asyncs

    for (int t = 0; t < NT; ++t) {
        const int bufc = t & 1;
        if (t + 1 < NT) stage(bufc ^ 1, t + 1);   // overlap with MFMA below
        #pragma unroll
        for (int kk = 0; kk < 2; ++kk) {
            bf16x8 a[4], b[4];
            #pragma unroll
            for (int i = 0; i < 4; ++i) {
                int m = wm + i*16 + l15;
                int ca = (kk*4 + quad) ^ (m & 7);
                a[i] = *(const bf16x8*)&As[bufc][m*64 + ca*8];
                int n = wn + i*16 + l15;
                int cbx = (kk*4 + quad) ^ (n & 7);
                b[i] = *(const bf16x8*)&Bs[bufc][n*64 + cbx*8];
            }
            #pragma unroll
            for (int i = 0; i < 4; ++i)
                #pragma unroll
                for (int j = 0; j < 4; ++j)
                    acc[i][j] = __builtin_amdgcn_mfma_f32_16x16x32_bf16(a[i], b[j], acc[i][j], 0, 0, 0);
        }
        __syncthreads();   // drains next-tile asyncs; protects buffer reuse
    }

    if (VFRAG && n0 >= 2*CDIM) {
        // ---- V tile: write PV 16x16x32 B-fragments straight to Vt ----
        #pragma unroll
        for (int i = 0; i < 4; ++i) {
            int gm = m0 + wm + i*16 + quad*4;      // seq base for r=0..3
            int bb = gm >> 11;                     // batch
            int kt = (gm & 2047) >> 6;             // 64-key tile
            int t  = i >> 1;                       // 32-key block within tile
            int wj = (i & 1) * 4;                  // word offset in fragment
            #pragma unroll
            for (int j = 0; j < 4; ++j) {
                int gn = n0 + wn + j*16 + l15;
                float bv = bias[gn];
                int d = gn - 2*CDIM;
                int h = d >> 6, jd = (d & 63) >> 4;  // jd == j
                int bh = bb * NHEADS + h;
                u32 p0 = prnd(acc[i][j][0] + bv);
                u32 p1 = prnd(acc[i][j][1] + bv);
                u32 p2 = prnd(acc[i][j][2] + bv);
                u32 p3 = prnd(acc[i][j][3] + bv);
                uint2 st;
                st.x = __builtin_amdgcn_perm(p1, p0, 0x07060302u);
                st.y = __builtin_amdgcn_perm(p3, p2, 0x07060302u);
                *(uint2*)(Vt + ((size_t)(bh*32 + kt))*VTILE
                             + (size_t)((t*4 + jd)*64 + lane)*8 + wj) = st;
            }
        }
    } else {
        #pragma unroll
        for (int i = 0; i < 4; ++i) {
            #pragma unroll
            for (int j = 0; j < 4; ++j) {
                int gn = n0 + wn + j*16 + l15;
                float bv = bias[gn];
                float sc = (gn < qn) ? qscale : 1.0f;
                #pragma unroll
                for (int r = 0; r < 4; ++r) {
                    int gm = m0 + wm + i*16 + quad*4 + r;
                    float v = (acc[i][j][r] + bv) * sc;
                    if (OUTF32) ((float*)Y)[(size_t)gm * N + gn] = v;
                    else        ((u16*)Y)[(size_t)gm * N + gn] = f2b(v);
                }
            }
        }
    }
}

// ---------------------------------------------------------------------------
// MFMA flash attention, PAIRED K-TILES (1 barrier per 2 tiles).
// Round-11 counters: MfmaUtil 38 + VALU 45 = 83% issue-sum; residual ~17%
// is the per-tile __syncthreads drain (~320 cyc of ~1540/tile). Session
// evidence says barrier amortization is first-order (r10: doubling GEMM
// barriers cost 14us). Here: 4-deep K/V buffers as a PAIR-level double
// buffer — stage tiles 2s+2,2s+3 before computing 2s,2s+1, ONE barrier per
// super-step. Barriers 32->16; prefetch gets 2 tile-computations of flight.
// LDS 48KB/block -> 3 blocks/CU retained (144 <= 160KB; occupancy is the
// dominant overlap mechanism here, r8).
// Core math unchanged (best measured 61.4-62.9us): S^T = K.Q^T, exp2
// in-register (log2e folded into q upstream), P packed prnd+v_perm into
// bf16x8 A-fragments matching the Vt fragment layout -> full-rate 16x16x32
// PV, no cross-lane shuffle. Zero-C first S-half. V split: idx-0 half LDS,
// idx-1 half direct-global (pipe balance, r2/r4). setprio around MFMA
// clusters (T5). XCD swizzle (T1): FETCH 104->18.5MB.
// ---------------------------------------------------------------------------
__global__ __launch_bounds__(256, 3)
void attn_mfma(const u16* __restrict__ QK, const u16* __restrict__ Vt,
               u16* __restrict__ Oa)
{
    __shared__ __align__(16) u16 Ks[2][2][64*64];   // [pair][tile-in-pair]
    __shared__ __align__(16) u16 Vls[2][2][2048];

    const int tid = threadIdx.x;
    const int wid = tid >> 6, lane = tid & 63;
    const int l15 = lane & 15, quad = lane >> 4;
    // ---- XCD swizzle: nwg = 16*48 = 768, 96 logical blocks per XCD ----
    const int fid = blockIdx.y * gridDim.x + blockIdx.x;
    const int swz = (fid & 7) * 96 + (fid >> 3);
    const int qt = swz & 15, bh = swz >> 4;
    const int b = bh / NHEADS, h = bh % NHEADS;

    const u16* Qg  = QK + ((size_t)(b*SEQ + qt*QROWS)) * NQKV + h*HDIM;
    const u16* Kg0 = QK + ((size_t)(b*SEQ)) * NQKV + CDIM + h*HDIM;
    const u16* Vg  = Vt + (size_t)bh * 32 * VTILE;   // + kt*VTILE per tile

    // stage tiles kt, kt+1 into pair wp
    auto stage2 = [&](int wp, int kt) {
        #pragma unroll
        for (int u = 0; u < 2; ++u) {
            #pragma unroll
            for (int r = 0; r < 2; ++r) {
                int li = r*256 + tid, row = li >> 3, c = li & 7, gc = c ^ (row & 7);
                ASYNC16(Kg0 + (size_t)((kt+u)*64 + row) * NQKV + gc*8, &Ks[wp][u][li*8]);
            }
            ASYNC16(Vg + (size_t)(kt+u) * VTILE + tid*8, &Vls[wp][u][tid*8]);
        }
    };

    // ---- prologue: stage tiles 0,1; Q frags straight to registers ----
    stage2(0, 0);

    // Q as B-operand of 16x16x32: B[n=l15][k=quad*8+jj]
    bf16x8 qf[2][2];
    #pragma unroll
    for (int mb = 0; mb < 2; ++mb)
        #pragma unroll
        for (int kk = 0; kk < 2; ++kk)
            qf[mb][kk] = *(const bf16x8*)(Qg + (size_t)(wid*32 + mb*16 + l15) * NQKV + kk*32 + quad*8);

    const bf16x8 ONES8 = { (short)0x3F80, (short)0x3F80, (short)0x3F80, (short)0x3F80,
                           (short)0x3F80, (short)0x3F80, (short)0x3F80, (short)0x3F80 };
    const f32x4 ZERO4 = { 0.f, 0.f, 0.f, 0.f };

    f32x4 o[2][4];
    #pragma unroll
    for (int mb = 0; mb < 2; ++mb)
        #pragma unroll
        for (int j = 0; j < 4; ++j)
            #pragma unroll
            for (int r = 0; r < 4; ++r) o[mb][j][r] = 0.f;
    f32x4 ll[2];
    #pragma unroll
    for (int mb = 0; mb < 2; ++mb)
        #pragma unroll
        for (int r = 0; r < 4; ++r) ll[mb][r] = 0.f;

    __syncthreads();   // drains prologue asyncs

    // compute one tile from pair rp, slot u (no staging, no barrier inside)
    auto body = [&](int kt, int rp, int u) {
        // ---- V fragments: idx-0 from LDS (2-way alias, conflict-free),
        //      idx-1 direct from global (coalesced 16B/lane, L2-hit).
        bf16x8 vf[2][4];
        #pragma unroll
        for (int jd = 0; jd < 4; ++jd) {
            vf[0][jd] = *(const bf16x8*)&Vls[rp][u][(size_t)(jd*64 + lane)*8];
            vf[1][jd] = *(const bf16x8*)(Vg + (size_t)kt * VTILE
                                         + (size_t)((4 + jd)*64 + lane)*8);
        }

        // ---- S^T = K.Q^T : s[mb][j][r] = S[q=mb-block+l15][k=j*16+quad*4+r]
        // kk=0 with zero C-operand (no accumulator init), kk=1 accumulates.
        f32x4 s[2][4];
        __builtin_amdgcn_s_setprio(1);
        #pragma unroll
        for (int j = 0; j < 4; ++j) {
            int kr = j*16 + l15;
            int ck = quad ^ (kr & 7);
            bf16x8 ak = *(const bf16x8*)&Ks[rp][u][kr*64 + ck*8];
            #pragma unroll
            for (int mb = 0; mb < 2; ++mb)
                s[mb][j] = __builtin_amdgcn_mfma_f32_16x16x32_bf16(ak, qf[mb][0], ZERO4, 0, 0, 0);
        }
        #pragma unroll
        for (int j = 0; j < 4; ++j) {
            int kr = j*16 + l15;
            int ck = (4 + quad) ^ (kr & 7);
            bf16x8 ak = *(const bf16x8*)&Ks[rp][u][kr*64 + ck*8];
            #pragma unroll
            for (int mb = 0; mb < 2; ++mb)
                s[mb][j] = __builtin_amdgcn_mfma_f32_16x16x32_bf16(ak, qf[mb][1], s[mb][j], 0, 0, 0);
        }
        __builtin_amdgcn_s_setprio(0);

        // ---- p = 2^s in-register; pack to 16x16x32 A-fragments (prnd+perm) ----
        bf16x8 pf[2][2];
        #pragma unroll
        for (int mb = 0; mb < 2; ++mb)
            #pragma unroll
            for (int t = 0; t < 2; ++t) {
                u32 a0 = prnd(__builtin_amdgcn_exp2f(s[mb][2*t][0]));
                u32 a1 = prnd(__builtin_amdgcn_exp2f(s[mb][2*t][1]));
                u32 a2 = prnd(__builtin_amdgcn_exp2f(s[mb][2*t][2]));
                u32 a3 = prnd(__builtin_amdgcn_exp2f(s[mb][2*t][3]));
                u32 b0 = prnd(__builtin_amdgcn_exp2f(s[mb][2*t+1][0]));
                u32 b1 = prnd(__builtin_amdgcn_exp2f(s[mb][2*t+1][1]));
                u32 b2 = prnd(__builtin_amdgcn_exp2f(s[mb][2*t+1][2]));
                u32 b3 = prnd(__builtin_amdgcn_exp2f(s[mb][2*t+1][3]));
                union { uint4 u; bf16x8 v; } cst;
                cst.u.x = __builtin_amdgcn_perm(a1, a0, 0x07060302u);
                cst.u.y = __builtin_amdgcn_perm(a3, a2, 0x07060302u);
                cst.u.z = __builtin_amdgcn_perm(b1, b0, 0x07060302u);
                cst.u.w = __builtin_amdgcn_perm(b3, b2, 0x07060302u);
                pf[mb][t] = cst.v;
            }

        // ---- O += P V ; l += P . 1 ----
        __builtin_amdgcn_s_setprio(1);
        #pragma unroll
        for (int t = 0; t < 2; ++t) {
            #pragma unroll
            for (int jd = 0; jd < 4; ++jd) {
                #pragma unroll
                for (int mb = 0; mb < 2; ++mb)
                    o[mb][jd] = __builtin_amdgcn_mfma_f32_16x16x32_bf16(pf[mb][t], vf[t][jd], o[mb][jd], 0, 0, 0);
            }
            #pragma unroll
            for (int mb = 0; mb < 2; ++mb)
                ll[mb] = __builtin_amdgcn_mfma_f32_16x16x32_bf16(pf[mb][t], ONES8, ll[mb], 0, 0, 0);
        }
        __builtin_amdgcn_s_setprio(0);
    };

    // 32 tiles as 16 super-steps; pair rp = s&1, write pair wp = rp^1
    for (int s = 0; s < 16; ++s) {
        const int rp = s & 1, wp = rp ^ 1;
        if (s < 15) stage2(wp, 2*s + 2);   // in flight across both bodies
        body(2*s,     rp, 0);
        body(2*s + 1, rp, 1);
        __syncthreads();   // drains pair prefetch; protects pair reuse
    }

    // ---- epilogue: O rows q = quad*4+r, cols d = jd*16+l15; l same layout ----
    u16* Og = Oa + ((size_t)(b*SEQ + qt*QROWS)) * CDIM + h*HDIM;
    #pragma unroll
    for (int mb = 0; mb < 2; ++mb) {
        #pragma unroll
        for (int r = 0; r < 4; ++r) {
            float inv = 1.f / ll[mb][r];
            int row = wid*32 + mb*16 + quad*4 + r;
            #pragma unroll
            for (int jd = 0; jd < 4; ++jd)
                Og[(size_t)row * CDIM + jd*16 + l15] = f2b(o[mb][jd][r] * inv);
        }
    }
}

// ---------------------------------------------------------------------------
extern "C" void kernel_launch(void* const* d_in, const int* in_sizes, int n_in,
                              void* d_out, int out_size, void* d_ws, size_t ws_size,
                              hipStream_t stream)
{
    const float* x  = (const float*)d_in[0];
    const float* Wq = (const float*)d_in[1];
    const float* bq = (const float*)d_in[2];
    const float* Wk = (const float*)d_in[3];
    const float* bk = (const float*)d_in[4];
    const float* Wv = (const float*)d_in[5];
    const float* bv = (const float*)d_in[6];
    const float* Wo = (const float*)d_in[7];
    const float* bo = (const float*)d_in[8];

    unsigned char* ws = (unsigned char*)d_ws;
    u16* xb   = (u16*)ws;  ws += (size_t)MTOT * CDIM * 2;
    u16* wqkv = (u16*)ws;  ws += (size_t)NQKV * CDIM * 2;
    u16* wob  = (u16*)ws;  ws += (size_t)CDIM * CDIM * 2;
    float* bcat = (float*)ws; ws += (size_t)NQKV * 4;
    u16* qkv  = (u16*)ws;  ws += (size_t)MTOT * NQKV * 2;
    u16* vt   = (u16*)ws;  ws += (size_t)BATCH*NHEADS*32*VTILE * 2;
    u16* ao   = (u16*)ws;

    prep_kern<<<XBLK + 4*WBLK + 9, 256, 0, stream>>>(x, Wq, Wk, Wv, Wo, bq, bk, bv,
                                                     xb, wqkv, wob, bcat);

    // q pre-scaled by log2(e)/sqrt(HDIM) so softmax is a bare exp2
    gemm_bf16<0,1><<<dim3(NQKV/128, MTOT/128), 256, 0, stream>>>(xb, wqkv, bcat, qkv, vt, NQKV, CDIM, CDIM, 0.18033688f);
    attn_mfma<<<dim3(SEQ/QROWS, BATCH*NHEADS), 256, 0, stream>>>(qkv, vt, ao);
    gemm_bf16<1,0><<<dim3(CDIM/128, MTOT/128), 256, 0, stream>>>(ao, wob, bo, (float*)d_out, nullptr, CDIM, CDIM, 0, 1.0f);
}